// Round 4
// baseline (415.934 us; speedup 1.0000x reference)
//
#include <hip/hip_runtime.h>
#include <hip/hip_bf16.h>
#include <cstdint>
#include <cstddef>

// ActorHead fused pipeline, bf16 MFMA throughout.
//   K1 k_qkv : LDS-tiled GEMM-BT [4096x1536x512], 128x64 tiles (768 wgs)
//              -> Qb row-major (scaled), Kp/Vp MFMA-fragment-packed
//   K2 k_attn: split-K(S=8) flash attention, S^T ordering, P register-resident.
//              FULL chunk-state double-buffer (K,V,mask,weight in A/B register
//              sets): compute chunk t from set A while set B's loads (issued one
//              compute-phase earlier) are in flight -> load-to-use stall ~250cy
//              eliminated (R3 showed per-iter slot 574cy vs ~200cy issue work;
//              K/V loads issued ~30cy before first use was the gap).
//              sp = bx % S keeps each XCD on ONE split (K/V 1MB, L2-resident,
//              FETCH 137->98MB verified R3). launch_bounds(256,4): 128 unified
//              regs; A/B sets ~120 -> no spill ((256,8) spilled, R2: FETCH 484MB).
//   K2b k_comb: merge splits, influence, valid
//   K3 k_fold: fold out_w over heads; K4 k_out: [4096x128x512] GEMM (256 wgs)
// d_out = topic[4096*128] fp32 ++ influence[4096] fp32

typedef __attribute__((ext_vector_type(8))) short bf16x8;
typedef __attribute__((ext_vector_type(4))) short bf16x4;
typedef __attribute__((ext_vector_type(4))) float f32x4;

#define MFMA32(a, b, c) __builtin_amdgcn_mfma_f32_16x16x32_bf16((a), (b), (c), 0, 0, 0)
// K=16 bf16 MFMA: gfx90a-era "_1k" spelling; maps to v_mfma_f32_16x16x16_bf16 (valid gfx950).
#define MFMA16(a, b, c) __builtin_amdgcn_mfma_f32_16x16x16bf16_1k((a), (b), (c), 0, 0, 0)

static __device__ __forceinline__ short f2b(float x) {
  union { float f; unsigned u; } v; v.f = x;
  unsigned r = v.u + 0x7fffu + ((v.u >> 16) & 1u);  // RNE to bf16
  return (short)(r >> 16);
}

// ---------------- K1: QKV projection (LDS-tiled 128x64, packed epilogue) ----------------
__global__ __launch_bounds__(256) void k_qkv(
    const float* __restrict__ a, const float* __restrict__ kv,
    const float* __restrict__ w, const float* __restrict__ bias,
    short* __restrict__ Qb, short* __restrict__ Kp, short* __restrict__ Vp)
{
  __shared__ short As[128 * 40];
  __shared__ short Bs[64 * 40];
  const int blk = blockIdx.x;
  const int bm = blk % 32, bn = blk / 32;  // bn 0..23; consecutive blocks share w-slice
  const int m0 = bm * 128, n0 = bn * 64;
  const float* __restrict__ Ain = (bn < 8) ? a : kv;
  const int tid = threadIdx.x;
  const int lane = tid & 63, wvi = tid >> 6;
  const int wm = (wvi >> 1) * 64, wn = (wvi & 1) * 32;
  const int c = lane & 15, g = lane >> 4;
  const int srA = tid >> 1, scA = (tid & 1) * 16;
  const int srB = tid >> 2, scB = (tid & 3) * 8;

  f32x4 acc[4][2];
#pragma unroll
  for (int i = 0; i < 4; ++i)
#pragma unroll
    for (int j = 0; j < 2; ++j) acc[i][j] = (f32x4)0.f;

  for (int k0 = 0; k0 < 512; k0 += 32) {
    const float* ap = Ain + (size_t)(m0 + srA) * 512 + k0 + scA;
#pragma unroll
    for (int j = 0; j < 4; ++j) {
      f32x4 av = *(const f32x4*)(ap + 4 * j);
      bf16x4 as;
      as.x = f2b(av.x); as.y = f2b(av.y); as.z = f2b(av.z); as.w = f2b(av.w);
      *(bf16x4*)(&As[srA * 40 + scA + 4 * j]) = as;
    }
    const float* bp = w + (size_t)(n0 + srB) * 512 + k0 + scB;
#pragma unroll
    for (int j = 0; j < 2; ++j) {
      f32x4 bv = *(const f32x4*)(bp + 4 * j);
      bf16x4 bs;
      bs.x = f2b(bv.x); bs.y = f2b(bv.y); bs.z = f2b(bv.z); bs.w = f2b(bv.w);
      *(bf16x4*)(&Bs[srB * 40 + scB + 4 * j]) = bs;
    }
    __syncthreads();
    bf16x8 af[4], bfg[2];
#pragma unroll
    for (int t = 0; t < 4; ++t)
      af[t] = *(const bf16x8*)(&As[(wm + t * 16 + c) * 40 + g * 8]);
#pragma unroll
    for (int t = 0; t < 2; ++t)
      bfg[t] = *(const bf16x8*)(&Bs[(wn + t * 16 + c) * 40 + g * 8]);
#pragma unroll
    for (int rt = 0; rt < 4; ++rt)
#pragma unroll
      for (int ct = 0; ct < 2; ++ct)
        acc[rt][ct] = MFMA32(af[rt], bfg[ct], acc[rt][ct]);
    __syncthreads();
  }

#pragma unroll
  for (int ct = 0; ct < 2; ++ct) {
    const int col = n0 + wn + ct * 16 + c;
    const float bj = bias[col];
#pragma unroll
    for (int rt = 0; rt < 4; ++rt) {
      const int row = m0 + wm + rt * 16 + g * 4;  // row&15 = g*4
      const int mc = row >> 4;
      if (col < 512) {
#pragma unroll
        for (int r = 0; r < 4; ++r)
          Qb[(size_t)(row + r) * 512 + col] = f2b((acc[rt][ct][r] + bj) * 0.08838834764831843f);
      } else if (col < 1024) {
        const int colK = col - 512;
        const int h = colK >> 7, dk = colK & 127;
        const int ks = dk >> 5, gk = (dk >> 3) & 3, j = dk & 7;
        short* base = Kp + (size_t)((((h * 256 + mc) * 4 + ks) * 64) + gk * 16 + g * 4) * 8 + j;
#pragma unroll
        for (int r = 0; r < 4; ++r) base[r * 8] = f2b(acc[rt][ct][r] + bj);
      } else {
        const int colV = col - 1024;
        const int h = colV >> 7, db = (colV & 127) >> 4, cv = colV & 15;
        bf16x4 pk;
#pragma unroll
        for (int r = 0; r < 4; ++r) pk[r] = f2b(acc[rt][ct][r] + bj);
        *(bf16x4*)(Vp + (size_t)((((h * 256 + mc) * 8 + db) * 64) + g * 16 + cv) * 4) = pk;
      }
    }
  }
}

// ---------------- K2: split-K flash attention (A/B chunk double-buffer) ----------------
__global__ __launch_bounds__(256, 4) void k_attn(
    const short* __restrict__ Qb, const short* __restrict__ Kp,
    const short* __restrict__ Vp, const float* __restrict__ wgt,
    const int* __restrict__ msk, const int S,
    short* __restrict__ Opart, float* __restrict__ lpart,
    float* __restrict__ cipart, float* __restrict__ lbpart)
{
  const int bx = blockIdx.x;
  // sp = bx % S: with round-robin block->XCD dispatch (XCD = bx % 8) every XCD
  // serves exactly one split (S=8) -> per-XCD K/V working set 1 MB, L2-resident.
  const int sp = bx % S, rb = bx / S;
  const int n0 = rb * 16;
  const int mlen = 4096 / S;
  const int mc0 = (sp * mlen) >> 4;
  const int nch = mlen >> 4;
  const int tid = threadIdx.x;
  const int lane = tid & 63, h = tid >> 6;
  const int c = lane & 15, g = lane >> 4;

  bf16x8 qf[4];
#pragma unroll
  for (int ks = 0; ks < 4; ++ks)
    qf[ks] = *(const bf16x8*)(Qb + (size_t)(n0 + c) * 512 + h * 128 + ks * 32 + g * 8);

  f32x4 O[8];
#pragma unroll
  for (int db = 0; db < 8; ++db) O[db] = (f32x4)0.f;
  float lh = 0.f, lb = 0.f, ci = 0.f;

  const short* Kw = Kp + (size_t)h * 524288 + (size_t)lane * 8 + (size_t)mc0 * 2048;
  const short* Vw = Vp + (size_t)h * 524288 + (size_t)lane * 4 + (size_t)mc0 * 2048;
  const int* mbase_p = msk + (size_t)(n0 + c) * 4096 + g * 4 + (size_t)mc0 * 16;
  const float* wbase_p = wgt + (size_t)(n0 + c) * 4096 + g * 4 + (size_t)mc0 * 16;

  // A/B chunk-state register sets (K 16 + V 16 + m/w 8 VGPRs each)
  bf16x8 kA[4], kB[4];
  bf16x4 vA[8], vB[8];
  int4 mA, mB;
  f32x4 wA, wB;

  // Load one chunk's full state. Issue order: K (oldest) -> V -> mask -> weight,
  // so the consumer's implicit vmcnt waits retire exactly this set while the
  // other set's (younger) loads stay in flight.
  auto LOAD = [&](bf16x8 (&kf)[4], bf16x4 (&vf)[8], int4& mk, f32x4& wv, int tt) {
#pragma unroll
    for (int ks = 0; ks < 4; ++ks)
      kf[ks] = *(const bf16x8*)(Kw + tt * 2048 + ks * 512);
#pragma unroll
    for (int db = 0; db < 8; ++db)
      vf[db] = *(const bf16x4*)(Vw + tt * 2048 + db * 256);
    mk = *(const int4*)(mbase_p + tt * 16);
    wv = *(const f32x4*)(wbase_p + tt * 16);
  };

  auto COMPUTE = [&](const bf16x8 (&kf)[4], const bf16x4 (&vf)[8],
                     const int4 mk, const f32x4 wv) {
    f32x4 Sv = (f32x4)0.f;
#pragma unroll
    for (int ks = 0; ks < 4; ++ks) Sv = MFMA32(kf[ks], qf[ks], Sv);
    const float e0 = mk.x ? __expf(wv.x) : 0.f;
    const float e1 = mk.y ? __expf(wv.y) : 0.f;
    const float e2 = mk.z ? __expf(wv.z) : 0.f;
    const float e3 = mk.w ? __expf(wv.w) : 0.f;
    const float p0 = __expf(Sv[0]) * e0, p1 = __expf(Sv[1]) * e1;
    const float p2 = __expf(Sv[2]) * e2, p3 = __expf(Sv[3]) * e3;
    lh += (p0 + p1) + (p2 + p3);
    lb += (e0 + e1) + (e2 + e3);
    ci += (p0 * e0 + p1 * e1) + (p2 * e2 + p3 * e3);
    bf16x4 pa;
    pa[0] = f2b(p0); pa[1] = f2b(p1); pa[2] = f2b(p2); pa[3] = f2b(p3);
#pragma unroll
    for (int db = 0; db < 8; ++db)
      O[db] = MFMA16(pa, vf[db], O[db]);
  };

  // Prologue: fill both buffers (nch >= 32 for S <= 8, always even).
  LOAD(kA, vA, mA, wA, 0);
  LOAD(kB, vB, mB, wB, 1);

  for (int t = 0; t < nch; t += 2) {
    // compute chunk t (set A, loads issued one compute-phase ago), then refill A
    COMPUTE(kA, vA, mA, wA);
    int t2 = t + 2; if (t2 >= nch) t2 = nch - 1;  // clamped redundant load on tail
    LOAD(kA, vA, mA, wA, t2);
    // compute chunk t+1 (set B), then refill B
    COMPUTE(kB, vB, mB, wB);
    int t3 = t + 3; if (t3 >= nch) t3 = nch - 1;
    LOAD(kB, vB, mB, wB, t3);
  }

  // reduce over g-groups (lanes ^16, ^32 share actor n=c)
  lh += __shfl_xor(lh, 16, 64); lh += __shfl_xor(lh, 32, 64);
  lb += __shfl_xor(lb, 16, 64); lb += __shfl_xor(lb, 32, 64);
  ci += __shfl_xor(ci, 16, 64); ci += __shfl_xor(ci, 32, 64);

  float inv[4];
#pragma unroll
  for (int r = 0; r < 4; ++r)
    inv[r] = 1.f / fmaxf(__shfl(lh, 4 * g + r, 64), 1e-30f);
#pragma unroll
  for (int db = 0; db < 8; ++db)
#pragma unroll
    for (int r = 0; r < 4; ++r)
      Opart[(size_t)sp * (4096 * 512) + (size_t)(n0 + g * 4 + r) * 512 +
            h * 128 + db * 16 + c] = f2b(O[db][r] * inv[r]);

  if (g == 0) {
    const int row = n0 + c;
    lpart[((size_t)sp * 4 + h) * 4096 + row] = lh;
    cipart[((size_t)sp * 4 + h) * 4096 + row] = ci;
    if (h == 0) lbpart[(size_t)sp * 4096 + row] = lb;
  }
}

// ---------------- K2b: combine splits ----------------
__global__ __launch_bounds__(256) void k_comb(
    const short* __restrict__ Opart, const float* __restrict__ lpart,
    const float* __restrict__ cipart, const float* __restrict__ lbpart,
    const int S, short* __restrict__ ctxb, float* __restrict__ validw,
    float* __restrict__ infl)
{
  const int tid = threadIdx.x;
  const int rloc = tid >> 5, cseg = tid & 31;
  const int row = blockIdx.x * 8 + rloc;
  const int col0 = cseg * 16;
  const int h = col0 >> 7;

  float l[4], ciS[4], lb = 0.f;
#pragma unroll
  for (int hh = 0; hh < 4; ++hh) { l[hh] = 0.f; ciS[hh] = 0.f; }
  for (int s = 0; s < S; ++s) {
#pragma unroll
    for (int hh = 0; hh < 4; ++hh) {
      l[hh]   += lpart[((size_t)s * 4 + hh) * 4096 + row];
      ciS[hh] += cipart[((size_t)s * 4 + hh) * 4096 + row];
    }
    lb += lbpart[(size_t)s * 4096 + row];
  }

  float acc[16];
#pragma unroll
  for (int j = 0; j < 16; ++j) acc[j] = 0.f;
  const float linv = 1.f / fmaxf(l[h], 1e-30f);
  for (int s = 0; s < S; ++s) {
    const float w_s = lpart[((size_t)s * 4 + h) * 4096 + row] * linv;
    const bf16x8 o0 = *(const bf16x8*)(Opart + (size_t)s * (4096 * 512) + (size_t)row * 512 + col0);
    const bf16x8 o1 = *(const bf16x8*)(Opart + (size_t)s * (4096 * 512) + (size_t)row * 512 + col0 + 8);
#pragma unroll
    for (int j = 0; j < 8; ++j) {
      union { unsigned u; float f; } v0, v1;
      v0.u = ((unsigned)(unsigned short)o0[j]) << 16;
      v1.u = ((unsigned)(unsigned short)o1[j]) << 16;
      acc[j]     += w_s * v0.f;
      acc[8 + j] += w_s * v1.f;
    }
  }
  bf16x8 c0, c1;
#pragma unroll
  for (int j = 0; j < 8; ++j) { c0[j] = f2b(acc[j]); c1[j] = f2b(acc[8 + j]); }
  *(bf16x8*)(ctxb + (size_t)row * 512 + col0) = c0;
  *(bf16x8*)(ctxb + (size_t)row * 512 + col0 + 8) = c1;

  if (cseg == 0) {
    validw[row] = (lb > 0.f) ? 1.f : 0.f;
    float s_ = 0.f;
#pragma unroll
    for (int hh = 0; hh < 4; ++hh) s_ += ciS[hh] / fmaxf(l[hh], 1e-30f);
    infl[row] = (lb > 0.f) ? s_ / (4.f * lb) : 0.f;
  }
}

// ---------------- K3: fold out_w over heads ----------------
__global__ void k_fold(const float* __restrict__ ow, const float* __restrict__ ob,
                       short* __restrict__ Wf, float* __restrict__ bfo)
{
  const int idx = blockIdx.x * 256 + threadIdx.x;
  if (idx < 128 * 512) {
    const int dk = idx >> 9, d = idx & 511;
    const float s = 0.25f * (ow[(size_t)dk * 512 + d] + ow[(size_t)(dk + 128) * 512 + d] +
                             ow[(size_t)(dk + 256) * 512 + d] + ow[(size_t)(dk + 384) * 512 + d]);
    Wf[(size_t)dk * 512 + d] = f2b(s);
  }
  if (idx < 128) bfo[idx] = 0.25f * (ob[idx] + ob[idx + 128] + ob[idx + 256] + ob[idx + 384]);
}

// ---------------- K4: topic = ctx @ Wfold^T + bfold (256 wgs, direct frags) ----------------
__global__ __launch_bounds__(256) void k_out(
    const short* __restrict__ ctxb, const short* __restrict__ Wf,
    const float* __restrict__ bfo, const float* __restrict__ validw,
    float* __restrict__ topic)
{
  const int tid = threadIdx.x;
  const int lane = tid & 63, wvi = tid >> 6;
  const int m0 = blockIdx.x * 16;
  const int c = lane & 15, g = lane >> 4;

  f32x4 acc[2];
  acc[0] = (f32x4)0.f; acc[1] = (f32x4)0.f;

  for (int k0 = 0; k0 < 512; k0 += 32) {
    const bf16x8 af = *(const bf16x8*)(ctxb + (size_t)(m0 + c) * 512 + k0 + g * 8);
#pragma unroll
    for (int dbl = 0; dbl < 2; ++dbl) {
      const bf16x8 bfr = *(const bf16x8*)(Wf + (size_t)(wvi * 32 + dbl * 16 + c) * 512 + k0 + g * 8);
      acc[dbl] = MFMA32(af, bfr, acc[dbl]);
    }
  }

#pragma unroll
  for (int r = 0; r < 4; ++r) {
    const int row = m0 + g * 4 + r;
    const float va = validw[row];
#pragma unroll
    for (int dbl = 0; dbl < 2; ++dbl) {
      const int col = wvi * 32 + dbl * 16 + c;
      const float vl = (va > 0.5f) ? (acc[dbl][r] + bfo[col]) : 0.f;
      topic[(size_t)row * 128 + col] = vl;
    }
  }
}

extern "C" void kernel_launch(void* const* d_in, const int* in_sizes, int n_in,
                              void* d_out, int out_size, void* d_ws, size_t ws_size,
                              hipStream_t stream) {
  const float* a_z  = (const float*)d_in[0];
  const float* bv_z = (const float*)d_in[1];
  const int*   mask = (const int*)d_in[2];
  const float* wgt  = (const float*)d_in[3];
  const float* ipw  = (const float*)d_in[4];
  const float* ipb  = (const float*)d_in[5];
  const float* ow   = (const float*)d_in[6];
  const float* ob   = (const float*)d_in[7];
  float* topic = (float*)d_out;              // [4096 x 128]
  float* infl  = (float*)d_out + 4096 * 128; // [4096]

  const size_t MB = (size_t)1 << 20;
  char* ws = (char*)d_ws;
  short* Qb     = (short*)(ws);                    // 4 MB
  short* Kp     = (short*)(ws + 4 * MB);           // 4 MB packed K frags
  short* Vp     = (short*)(ws + 8 * MB);           // 4 MB packed V frags
  short* ctxb   = (short*)(ws + 12 * MB);          // 4 MB
  float* validw = (float*)(ws + 16 * MB);          // 16 KB
  short* Wf     = (short*)(ws + 16 * MB + (64 << 10));   // 128 KB
  float* bfo    = (float*)(ws + 16 * MB + (224 << 10));  // 512 B
  const size_t pbase0 = 16 * MB + (256 << 10);

  // per split: Opart 4MB + lpart 64KB + cipart 64KB + lbpart 16KB
  auto need = [&](int S) { return pbase0 + (size_t)S * (4 * MB + (144 << 10)); };
  int S = 8;
  while (S > 1 && need(S) > ws_size) S >>= 1;

  char* pbase = ws + pbase0;
  short* Opart  = (short*)(pbase);
  float* lpart  = (float*)(pbase + (size_t)S * 4 * MB);
  float* cipart = (float*)(pbase + (size_t)S * 4 * MB + ((size_t)S << 16));
  float* lbpart = (float*)(pbase + (size_t)S * 4 * MB + ((size_t)S << 17));

  k_qkv <<<768, 256, 0, stream>>>(a_z, bv_z, ipw, ipb, Qb, Kp, Vp);
  k_fold<<<256, 256, 0, stream>>>(ow, ob, Wf, bfo);
  k_attn<<<256 * S, 256, 0, stream>>>(Qb, Kp, Vp, wgt, mask, S, Opart, lpart, cipart, lbpart);
  k_comb<<<512, 256, 0, stream>>>(Opart, lpart, cipart, lbpart, S, ctxb, validw, infl);
  k_out <<<256, 256, 0, stream>>>(ctxb, Wf, bfo, validw, topic);
}

// Round 11
// 392.511 us; speedup vs baseline: 1.0597x; 1.0597x over previous
//
#include <hip/hip_runtime.h>
#include <hip/hip_bf16.h>
#include <cstdint>
#include <cstddef>

// ActorHead fused pipeline, bf16 MFMA throughout.
//   K1 k_qkv : LDS-tiled GEMM-BT [4096x1536x512], 128x64 tiles (768 wgs)
//              -> Qb row-major (scaled), Kp/Vp MFMA-fragment-packed
//   K2 k_attn: split-K(S=8) flash attention, S^T ordering, P register-resident.
//              R3 structure + DEPTH-2 mask/weight prefetch: m/w stream from
//              HBM (~900cy); depth-1 gave only ~574cy flight -> ~330cy/iter
//              stall. Two named m/w sets (A/B), unroll-2 loop, +8 VGPRs only.
//              K/V stay loaded in-iteration (R4's full A/B K/V dbuf hit the
//              128-unified-reg cap: VGPR pinned at 64, WRITE +12MB scratch
//              spill, 196->258us. REVERTED).
//              Sv split into 2 partial accumulators (halves dependent-MFMA chain).
//              sp = bx % S keeps each XCD on ONE split (K/V 1MB, L2-resident,
//              FETCH 137->98MB verified R3). launch_bounds(256,4): 128 unified.
//   K2b k_comb: merge splits, influence, valid
//   K3 k_fold: fold out_w over heads; K4 k_out: [4096x128x512] GEMM (256 wgs)
// d_out = topic[4096*128] fp32 ++ influence[4096] fp32

typedef __attribute__((ext_vector_type(8))) short bf16x8;
typedef __attribute__((ext_vector_type(4))) short bf16x4;
typedef __attribute__((ext_vector_type(4))) float f32x4;

#define MFMA32(a, b, c) __builtin_amdgcn_mfma_f32_16x16x32_bf16((a), (b), (c), 0, 0, 0)
// K=16 bf16 MFMA: gfx90a-era "_1k" spelling; maps to v_mfma_f32_16x16x16_bf16 (valid gfx950).
#define MFMA16(a, b, c) __builtin_amdgcn_mfma_f32_16x16x16bf16_1k((a), (b), (c), 0, 0, 0)

static __device__ __forceinline__ short f2b(float x) {
  union { float f; unsigned u; } v; v.f = x;
  unsigned r = v.u + 0x7fffu + ((v.u >> 16) & 1u);  // RNE to bf16
  return (short)(r >> 16);
}

// ---------------- K1: QKV projection (LDS-tiled 128x64, packed epilogue) ----------------
__global__ __launch_bounds__(256) void k_qkv(
    const float* __restrict__ a, const float* __restrict__ kv,
    const float* __restrict__ w, const float* __restrict__ bias,
    short* __restrict__ Qb, short* __restrict__ Kp, short* __restrict__ Vp)
{
  __shared__ short As[128 * 40];
  __shared__ short Bs[64 * 40];
  const int blk = blockIdx.x;
  const int bm = blk % 32, bn = blk / 32;  // bn 0..23; consecutive blocks share w-slice
  const int m0 = bm * 128, n0 = bn * 64;
  const float* __restrict__ Ain = (bn < 8) ? a : kv;
  const int tid = threadIdx.x;
  const int lane = tid & 63, wvi = tid >> 6;
  const int wm = (wvi >> 1) * 64, wn = (wvi & 1) * 32;
  const int c = lane & 15, g = lane >> 4;
  const int srA = tid >> 1, scA = (tid & 1) * 16;
  const int srB = tid >> 2, scB = (tid & 3) * 8;

  f32x4 acc[4][2];
#pragma unroll
  for (int i = 0; i < 4; ++i)
#pragma unroll
    for (int j = 0; j < 2; ++j) acc[i][j] = (f32x4)0.f;

  for (int k0 = 0; k0 < 512; k0 += 32) {
    const float* ap = Ain + (size_t)(m0 + srA) * 512 + k0 + scA;
#pragma unroll
    for (int j = 0; j < 4; ++j) {
      f32x4 av = *(const f32x4*)(ap + 4 * j);
      bf16x4 as;
      as.x = f2b(av.x); as.y = f2b(av.y); as.z = f2b(av.z); as.w = f2b(av.w);
      *(bf16x4*)(&As[srA * 40 + scA + 4 * j]) = as;
    }
    const float* bp = w + (size_t)(n0 + srB) * 512 + k0 + scB;
#pragma unroll
    for (int j = 0; j < 2; ++j) {
      f32x4 bv = *(const f32x4*)(bp + 4 * j);
      bf16x4 bs;
      bs.x = f2b(bv.x); bs.y = f2b(bv.y); bs.z = f2b(bv.z); bs.w = f2b(bv.w);
      *(bf16x4*)(&Bs[srB * 40 + scB + 4 * j]) = bs;
    }
    __syncthreads();
    bf16x8 af[4], bfg[2];
#pragma unroll
    for (int t = 0; t < 4; ++t)
      af[t] = *(const bf16x8*)(&As[(wm + t * 16 + c) * 40 + g * 8]);
#pragma unroll
    for (int t = 0; t < 2; ++t)
      bfg[t] = *(const bf16x8*)(&Bs[(wn + t * 16 + c) * 40 + g * 8]);
#pragma unroll
    for (int rt = 0; rt < 4; ++rt)
#pragma unroll
      for (int ct = 0; ct < 2; ++ct)
        acc[rt][ct] = MFMA32(af[rt], bfg[ct], acc[rt][ct]);
    __syncthreads();
  }

#pragma unroll
  for (int ct = 0; ct < 2; ++ct) {
    const int col = n0 + wn + ct * 16 + c;
    const float bj = bias[col];
#pragma unroll
    for (int rt = 0; rt < 4; ++rt) {
      const int row = m0 + wm + rt * 16 + g * 4;  // row&15 = g*4
      const int mc = row >> 4;
      if (col < 512) {
#pragma unroll
        for (int r = 0; r < 4; ++r)
          Qb[(size_t)(row + r) * 512 + col] = f2b((acc[rt][ct][r] + bj) * 0.08838834764831843f);
      } else if (col < 1024) {
        const int colK = col - 512;
        const int h = colK >> 7, dk = colK & 127;
        const int ks = dk >> 5, gk = (dk >> 3) & 3, j = dk & 7;
        short* base = Kp + (size_t)((((h * 256 + mc) * 4 + ks) * 64) + gk * 16 + g * 4) * 8 + j;
#pragma unroll
        for (int r = 0; r < 4; ++r) base[r * 8] = f2b(acc[rt][ct][r] + bj);
      } else {
        const int colV = col - 1024;
        const int h = colV >> 7, db = (colV & 127) >> 4, cv = colV & 15;
        bf16x4 pk;
#pragma unroll
        for (int r = 0; r < 4; ++r) pk[r] = f2b(acc[rt][ct][r] + bj);
        *(bf16x4*)(Vp + (size_t)((((h * 256 + mc) * 8 + db) * 64) + g * 16 + cv) * 4) = pk;
      }
    }
  }
}

// ---------------- K2: split-K flash attention (depth-2 m/w prefetch) ----------------
// One attention chunk: load K/V for chunk TT (oldest in vmcnt order), consume the
// m/w set loaded two iterations ago, refill that set for chunk TN (youngest ->
// stays in flight across the K/V wait).
#define ATTN_STEP(TT, MSET, WSET, TN)                                          \
  do {                                                                         \
    bf16x8 kf[4];                                                              \
    bf16x4 vf[8];                                                              \
    _Pragma("unroll")                                                          \
    for (int ks = 0; ks < 4; ++ks)                                             \
      kf[ks] = *(const bf16x8*)(Kw + (TT) * 2048 + ks * 512);                  \
    _Pragma("unroll")                                                          \
    for (int db = 0; db < 8; ++db)                                             \
      vf[db] = *(const bf16x4*)(Vw + (TT) * 2048 + db * 256);                  \
    const int4 mkC = MSET;                                                     \
    const f32x4 wvC = WSET;                                                    \
    MSET = *(const int4*)(mbase_p + (TN) * 16);                                \
    WSET = *(const f32x4*)(wbase_p + (TN) * 16);                               \
    f32x4 Sa = (f32x4)0.f, Sb = (f32x4)0.f;                                    \
    Sa = MFMA32(kf[0], qf[0], Sa);                                             \
    Sb = MFMA32(kf[2], qf[2], Sb);                                             \
    Sa = MFMA32(kf[1], qf[1], Sa);                                             \
    Sb = MFMA32(kf[3], qf[3], Sb);                                             \
    const float e0 = mkC.x ? __expf(wvC.x) : 0.f;                              \
    const float e1 = mkC.y ? __expf(wvC.y) : 0.f;                              \
    const float e2 = mkC.z ? __expf(wvC.z) : 0.f;                              \
    const float e3 = mkC.w ? __expf(wvC.w) : 0.f;                              \
    const float p0 = __expf(Sa[0] + Sb[0]) * e0;                               \
    const float p1 = __expf(Sa[1] + Sb[1]) * e1;                               \
    const float p2 = __expf(Sa[2] + Sb[2]) * e2;                               \
    const float p3 = __expf(Sa[3] + Sb[3]) * e3;                               \
    lh += (p0 + p1) + (p2 + p3);                                               \
    lb += (e0 + e1) + (e2 + e3);                                               \
    ci += (p0 * e0 + p1 * e1) + (p2 * e2 + p3 * e3);                           \
    bf16x4 pa;                                                                 \
    pa[0] = f2b(p0); pa[1] = f2b(p1); pa[2] = f2b(p2); pa[3] = f2b(p3);        \
    _Pragma("unroll")                                                          \
    for (int db = 0; db < 8; ++db)                                             \
      O[db] = MFMA16(pa, vf[db], O[db]);                                       \
  } while (0)

__global__ __launch_bounds__(256, 4) void k_attn(
    const short* __restrict__ Qb, const short* __restrict__ Kp,
    const short* __restrict__ Vp, const float* __restrict__ wgt,
    const int* __restrict__ msk, const int S,
    short* __restrict__ Opart, float* __restrict__ lpart,
    float* __restrict__ cipart, float* __restrict__ lbpart)
{
  const int bx = blockIdx.x;
  // sp = bx % S: with round-robin block->XCD dispatch (XCD = bx % 8) every XCD
  // serves exactly one split (S=8) -> per-XCD K/V working set 1 MB, L2-resident.
  const int sp = bx % S, rb = bx / S;
  const int n0 = rb * 16;
  const int mlen = 4096 / S;
  const int mc0 = (sp * mlen) >> 4;
  const int nch = mlen >> 4;  // 32 for S=8; always even for S in {1,2,4,8}
  const int tid = threadIdx.x;
  const int lane = tid & 63, h = tid >> 6;
  const int c = lane & 15, g = lane >> 4;

  bf16x8 qf[4];
#pragma unroll
  for (int ks = 0; ks < 4; ++ks)
    qf[ks] = *(const bf16x8*)(Qb + (size_t)(n0 + c) * 512 + h * 128 + ks * 32 + g * 8);

  f32x4 O[8];
#pragma unroll
  for (int db = 0; db < 8; ++db) O[db] = (f32x4)0.f;
  float lh = 0.f, lb = 0.f, ci = 0.f;

  const short* Kw = Kp + (size_t)h * 524288 + (size_t)lane * 8 + (size_t)mc0 * 2048;
  const short* Vw = Vp + (size_t)h * 524288 + (size_t)lane * 4 + (size_t)mc0 * 2048;
  const int* mbase_p = msk + (size_t)(n0 + c) * 4096 + g * 4 + (size_t)mc0 * 16;
  const float* wbase_p = wgt + (size_t)(n0 + c) * 4096 + g * 4 + (size_t)mc0 * 16;

  // depth-2 mask/weight prefetch: set A covers even chunks, B odd chunks.
  // Flight time = 2 iterations (~1100cy) > HBM latency (~900cy).
  int4 mA = *(const int4*)(mbase_p);
  f32x4 wA = *(const f32x4*)(wbase_p);
  int4 mB = *(const int4*)(mbase_p + 16);
  f32x4 wB = *(const f32x4*)(wbase_p + 16);

  for (int t = 0; t < nch; t += 2) {
    const int tn2 = (t + 2 < nch) ? (t + 2) : (nch - 1);  // clamped tail (unused)
    ATTN_STEP(t, mA, wA, tn2);
    const int tn3 = (t + 3 < nch) ? (t + 3) : (nch - 1);
    ATTN_STEP(t + 1, mB, wB, tn3);
  }

  // reduce over g-groups (lanes ^16, ^32 share actor n=c)
  lh += __shfl_xor(lh, 16, 64); lh += __shfl_xor(lh, 32, 64);
  lb += __shfl_xor(lb, 16, 64); lb += __shfl_xor(lb, 32, 64);
  ci += __shfl_xor(ci, 16, 64); ci += __shfl_xor(ci, 32, 64);

  float inv[4];
#pragma unroll
  for (int r = 0; r < 4; ++r)
    inv[r] = 1.f / fmaxf(__shfl(lh, 4 * g + r, 64), 1e-30f);
#pragma unroll
  for (int db = 0; db < 8; ++db)
#pragma unroll
    for (int r = 0; r < 4; ++r)
      Opart[(size_t)sp * (4096 * 512) + (size_t)(n0 + g * 4 + r) * 512 +
            h * 128 + db * 16 + c] = f2b(O[db][r] * inv[r]);

  if (g == 0) {
    const int row = n0 + c;
    lpart[((size_t)sp * 4 + h) * 4096 + row] = lh;
    cipart[((size_t)sp * 4 + h) * 4096 + row] = ci;
    if (h == 0) lbpart[(size_t)sp * 4096 + row] = lb;
  }
}

// ---------------- K2b: combine splits ----------------
__global__ __launch_bounds__(256) void k_comb(
    const short* __restrict__ Opart, const float* __restrict__ lpart,
    const float* __restrict__ cipart, const float* __restrict__ lbpart,
    const int S, short* __restrict__ ctxb, float* __restrict__ validw,
    float* __restrict__ infl)
{
  const int tid = threadIdx.x;
  const int rloc = tid >> 5, cseg = tid & 31;
  const int row = blockIdx.x * 8 + rloc;
  const int col0 = cseg * 16;
  const int h = col0 >> 7;

  float l[4], ciS[4], lb = 0.f;
#pragma unroll
  for (int hh = 0; hh < 4; ++hh) { l[hh] = 0.f; ciS[hh] = 0.f; }
  for (int s = 0; s < S; ++s) {
#pragma unroll
    for (int hh = 0; hh < 4; ++hh) {
      l[hh]   += lpart[((size_t)s * 4 + hh) * 4096 + row];
      ciS[hh] += cipart[((size_t)s * 4 + hh) * 4096 + row];
    }
    lb += lbpart[(size_t)s * 4096 + row];
  }

  float acc[16];
#pragma unroll
  for (int j = 0; j < 16; ++j) acc[j] = 0.f;
  const float linv = 1.f / fmaxf(l[h], 1e-30f);
  for (int s = 0; s < S; ++s) {
    const float w_s = lpart[((size_t)s * 4 + h) * 4096 + row] * linv;
    const bf16x8 o0 = *(const bf16x8*)(Opart + (size_t)s * (4096 * 512) + (size_t)row * 512 + col0);
    const bf16x8 o1 = *(const bf16x8*)(Opart + (size_t)s * (4096 * 512) + (size_t)row * 512 + col0 + 8);
#pragma unroll
    for (int j = 0; j < 8; ++j) {
      union { unsigned u; float f; } v0, v1;
      v0.u = ((unsigned)(unsigned short)o0[j]) << 16;
      v1.u = ((unsigned)(unsigned short)o1[j]) << 16;
      acc[j]     += w_s * v0.f;
      acc[8 + j] += w_s * v1.f;
    }
  }
  bf16x8 c0, c1;
#pragma unroll
  for (int j = 0; j < 8; ++j) { c0[j] = f2b(acc[j]); c1[j] = f2b(acc[8 + j]); }
  *(bf16x8*)(ctxb + (size_t)row * 512 + col0) = c0;
  *(bf16x8*)(ctxb + (size_t)row * 512 + col0 + 8) = c1;

  if (cseg == 0) {
    validw[row] = (lb > 0.f) ? 1.f : 0.f;
    float s_ = 0.f;
#pragma unroll
    for (int hh = 0; hh < 4; ++hh) s_ += ciS[hh] / fmaxf(l[hh], 1e-30f);
    infl[row] = (lb > 0.f) ? s_ / (4.f * lb) : 0.f;
  }
}

// ---------------- K3: fold out_w over heads ----------------
__global__ void k_fold(const float* __restrict__ ow, const float* __restrict__ ob,
                       short* __restrict__ Wf, float* __restrict__ bfo)
{
  const int idx = blockIdx.x * 256 + threadIdx.x;
  if (idx < 128 * 512) {
    const int dk = idx >> 9, d = idx & 511;
    const float s = 0.25f * (ow[(size_t)dk * 512 + d] + ow[(size_t)(dk + 128) * 512 + d] +
                             ow[(size_t)(dk + 256) * 512 + d] + ow[(size_t)(dk + 384) * 512 + d]);
    Wf[(size_t)dk * 512 + d] = f2b(s);
  }
  if (idx < 128) bfo[idx] = 0.25f * (ob[idx] + ob[idx + 128] + ob[idx + 256] + ob[idx + 384]);
}

// ---------------- K4: topic = ctx @ Wfold^T + bfold (256 wgs, direct frags) ----------------
__global__ __launch_bounds__(256) void k_out(
    const short* __restrict__ ctxb, const short* __restrict__ Wf,
    const float* __restrict__ bfo, const float* __restrict__ validw,
    float* __restrict__ topic)
{
  const int tid = threadIdx.x;
  const int lane = tid & 63, wvi = tid >> 6;
  const int m0 = blockIdx.x * 16;
  const int c = lane & 15, g = lane >> 4;

  f32x4 acc[2];
  acc[0] = (f32x4)0.f; acc[1] = (f32x4)0.f;

  for (int k0 = 0; k0 < 512; k0 += 32) {
    const bf16x8 af = *(const bf16x8*)(ctxb + (size_t)(m0 + c) * 512 + k0 + g * 8);
#pragma unroll
    for (int dbl = 0; dbl < 2; ++dbl) {
      const bf16x8 bfr = *(const bf16x8*)(Wf + (size_t)(wvi * 32 + dbl * 16 + c) * 512 + k0 + g * 8);
      acc[dbl] = MFMA32(af, bfr, acc[dbl]);
    }
  }

#pragma unroll
  for (int r = 0; r < 4; ++r) {
    const int row = m0 + g * 4 + r;
    const float va = validw[row];
#pragma unroll
    for (int dbl = 0; dbl < 2; ++dbl) {
      const int col = wvi * 32 + dbl * 16 + c;
      const float vl = (va > 0.5f) ? (acc[dbl][r] + bfo[col]) : 0.f;
      topic[(size_t)row * 128 + col] = vl;
    }
  }
}

extern "C" void kernel_launch(void* const* d_in, const int* in_sizes, int n_in,
                              void* d_out, int out_size, void* d_ws, size_t ws_size,
                              hipStream_t stream) {
  const float* a_z  = (const float*)d_in[0];
  const float* bv_z = (const float*)d_in[1];
  const int*   mask = (const int*)d_in[2];
  const float* wgt  = (const float*)d_in[3];
  const float* ipw  = (const float*)d_in[4];
  const float* ipb  = (const float*)d_in[5];
  const float* ow   = (const float*)d_in[6];
  const float* ob   = (const float*)d_in[7];
  float* topic = (float*)d_out;              // [4096 x 128]
  float* infl  = (float*)d_out + 4096 * 128; // [4096]

  const size_t MB = (size_t)1 << 20;
  char* ws = (char*)d_ws;
  short* Qb     = (short*)(ws);                    // 4 MB
  short* Kp     = (short*)(ws + 4 * MB);           // 4 MB packed K frags
  short* Vp     = (short*)(ws + 8 * MB);           // 4 MB packed V frags
  short* ctxb   = (short*)(ws + 12 * MB);          // 4 MB
  float* validw = (float*)(ws + 16 * MB);          // 16 KB
  short* Wf     = (short*)(ws + 16 * MB + (64 << 10));   // 128 KB
  float* bfo    = (float*)(ws + 16 * MB + (224 << 10));  // 512 B
  const size_t pbase0 = 16 * MB + (256 << 10);

  // per split: Opart 4MB + lpart 64KB + cipart 64KB + lbpart 16KB
  auto need = [&](int S) { return pbase0 + (size_t)S * (4 * MB + (144 << 10)); };
  int S = 8;
  while (S > 1 && need(S) > ws_size) S >>= 1;

  char* pbase = ws + pbase0;
  short* Opart  = (short*)(pbase);
  float* lpart  = (float*)(pbase + (size_t)S * 4 * MB);
  float* cipart = (float*)(pbase + (size_t)S * 4 * MB + ((size_t)S << 16));
  float* lbpart = (float*)(pbase + (size_t)S * 4 * MB + ((size_t)S << 17));

  k_qkv <<<768, 256, 0, stream>>>(a_z, bv_z, ipw, ipb, Qb, Kp, Vp);
  k_fold<<<256, 256, 0, stream>>>(ow, ob, Wf, bfo);
  k_attn<<<256 * S, 256, 0, stream>>>(Qb, Kp, Vp, wgt, mask, S, Opart, lpart, cipart, lbpart);
  k_comb<<<512, 256, 0, stream>>>(Opart, lpart, cipart, lbpart, S, ctxb, validw, infl);
  k_out <<<256, 256, 0, stream>>>(ctxb, Wf, bfo, validw, topic);
}

// Round 14
// 371.169 us; speedup vs baseline: 1.1206x; 1.0575x over previous
//
#include <hip/hip_runtime.h>
#include <hip/hip_bf16.h>
#include <cstdint>
#include <cstddef>

// ActorHead fused pipeline, bf16 MFMA throughout.
//   K1 k_qkv : LDS-tiled GEMM-BT [4096x1536x512], 128x64 tiles (768 wgs)
//   K2 k_attn: split-K(S=8) flash attention, 4 compute waves + 1 PRODUCER wave.
//     R11 lesson: vmcnt is IN-ORDER -> register prefetch of the HBM m/w stream
//     is pinned to depth-1 (next iter's K-wait retires older m/w loads). R0/R3/R11
//     all ~192-235us at identical traffic; closure: 128MB m/w / ~650GB/s = 197us
//     == measured. Each wave held only ~2 HBM loads in flight (Little's law cap).
//     FIX: wave 4 = dedicated producer staging m/w chunks via global_load_lds into
//     an 8-slot LDS ring, 7 chunks deep, counted s_waitcnt vmcnt(12) (never 0) +
//     raw s_barrier per chunk. Producer's vmcnt queue holds ONLY staging loads ->
//     depth holds; consumers read m/w via ds_read (lgkmcnt, decoupled from their
//     K/V vmcnt). TAIL FIX (pre-flight audit): producer ALWAYS issues 2 loads/iter
//     (source clamped to nch-1, raw slot) so the queue stays at 14 and vmcnt(12)
//     retires chunk t's loads on EVERY iteration — the R11 draft's conditional
//     issue let the queue drain in the last 6 iters, publishing unwritten LDS.
//     K/V stay direct (L2-resident: sp=bx%S XCD alignment, FETCH 98MB, R3).
//   K2b k_comb: merge splits; K3 k_fold; K4 k_out.
// d_out = topic[4096*128] fp32 ++ influence[4096] fp32

typedef __attribute__((ext_vector_type(8))) short bf16x8;
typedef __attribute__((ext_vector_type(4))) short bf16x4;
typedef __attribute__((ext_vector_type(4))) float f32x4;

#define MFMA32(a, b, c) __builtin_amdgcn_mfma_f32_16x16x32_bf16((a), (b), (c), 0, 0, 0)
#define MFMA16(a, b, c) __builtin_amdgcn_mfma_f32_16x16x16bf16_1k((a), (b), (c), 0, 0, 0)

static __device__ __forceinline__ short f2b(float x) {
  union { float f; unsigned u; } v; v.f = x;
  unsigned r = v.u + 0x7fffu + ((v.u >> 16) & 1u);  // RNE to bf16
  return (short)(r >> 16);
}

// ---------------- K1: QKV projection (LDS-tiled 128x64, packed epilogue) ----------------
__global__ __launch_bounds__(256) void k_qkv(
    const float* __restrict__ a, const float* __restrict__ kv,
    const float* __restrict__ w, const float* __restrict__ bias,
    short* __restrict__ Qb, short* __restrict__ Kp, short* __restrict__ Vp)
{
  __shared__ short As[128 * 40];
  __shared__ short Bs[64 * 40];
  const int blk = blockIdx.x;
  const int bm = blk % 32, bn = blk / 32;
  const int m0 = bm * 128, n0 = bn * 64;
  const float* __restrict__ Ain = (bn < 8) ? a : kv;
  const int tid = threadIdx.x;
  const int lane = tid & 63, wvi = tid >> 6;
  const int wm = (wvi >> 1) * 64, wn = (wvi & 1) * 32;
  const int c = lane & 15, g = lane >> 4;
  const int srA = tid >> 1, scA = (tid & 1) * 16;
  const int srB = tid >> 2, scB = (tid & 3) * 8;

  f32x4 acc[4][2];
#pragma unroll
  for (int i = 0; i < 4; ++i)
#pragma unroll
    for (int j = 0; j < 2; ++j) acc[i][j] = (f32x4)0.f;

  for (int k0 = 0; k0 < 512; k0 += 32) {
    const float* ap = Ain + (size_t)(m0 + srA) * 512 + k0 + scA;
#pragma unroll
    for (int j = 0; j < 4; ++j) {
      f32x4 av = *(const f32x4*)(ap + 4 * j);
      bf16x4 as;
      as.x = f2b(av.x); as.y = f2b(av.y); as.z = f2b(av.z); as.w = f2b(av.w);
      *(bf16x4*)(&As[srA * 40 + scA + 4 * j]) = as;
    }
    const float* bp = w + (size_t)(n0 + srB) * 512 + k0 + scB;
#pragma unroll
    for (int j = 0; j < 2; ++j) {
      f32x4 bv = *(const f32x4*)(bp + 4 * j);
      bf16x4 bs;
      bs.x = f2b(bv.x); bs.y = f2b(bv.y); bs.z = f2b(bv.z); bs.w = f2b(bv.w);
      *(bf16x4*)(&Bs[srB * 40 + scB + 4 * j]) = bs;
    }
    __syncthreads();
    bf16x8 af[4], bfg[2];
#pragma unroll
    for (int t = 0; t < 4; ++t)
      af[t] = *(const bf16x8*)(&As[(wm + t * 16 + c) * 40 + g * 8]);
#pragma unroll
    for (int t = 0; t < 2; ++t)
      bfg[t] = *(const bf16x8*)(&Bs[(wn + t * 16 + c) * 40 + g * 8]);
#pragma unroll
    for (int rt = 0; rt < 4; ++rt)
#pragma unroll
      for (int ct = 0; ct < 2; ++ct)
        acc[rt][ct] = MFMA32(af[rt], bfg[ct], acc[rt][ct]);
    __syncthreads();
  }

#pragma unroll
  for (int ct = 0; ct < 2; ++ct) {
    const int col = n0 + wn + ct * 16 + c;
    const float bj = bias[col];
#pragma unroll
    for (int rt = 0; rt < 4; ++rt) {
      const int row = m0 + wm + rt * 16 + g * 4;
      const int mc = row >> 4;
      if (col < 512) {
#pragma unroll
        for (int r = 0; r < 4; ++r)
          Qb[(size_t)(row + r) * 512 + col] = f2b((acc[rt][ct][r] + bj) * 0.08838834764831843f);
      } else if (col < 1024) {
        const int colK = col - 512;
        const int h = colK >> 7, dk = colK & 127;
        const int ks = dk >> 5, gk = (dk >> 3) & 3, j = dk & 7;
        short* base = Kp + (size_t)((((h * 256 + mc) * 4 + ks) * 64) + gk * 16 + g * 4) * 8 + j;
#pragma unroll
        for (int r = 0; r < 4; ++r) base[r * 8] = f2b(acc[rt][ct][r] + bj);
      } else {
        const int colV = col - 1024;
        const int h = colV >> 7, db = (colV & 127) >> 4, cv = colV & 15;
        bf16x4 pk;
#pragma unroll
        for (int r = 0; r < 4; ++r) pk[r] = f2b(acc[rt][ct][r] + bj);
        *(bf16x4*)(Vp + (size_t)((((h * 256 + mc) * 8 + db) * 64) + g * 16 + cv) * 4) = pk;
      }
    }
  }
}

// ---------------- K2: flash attention, producer-wave async m/w staging ----------------
#define MW_D    7   // chunks in flight
#define MW_RING 8   // ring slots (D+1); 8*2KB = 16KB LDS

typedef const __attribute__((address_space(1))) void* gas_p;
typedef __attribute__((address_space(3))) void* las_p;

__global__ __launch_bounds__(320, 4) void k_attn(
    const short* __restrict__ Qb, const short* __restrict__ Kp,
    const short* __restrict__ Vp, const float* __restrict__ wgt,
    const int* __restrict__ msk, const int S,
    short* __restrict__ Opart, float* __restrict__ lpart,
    float* __restrict__ cipart, float* __restrict__ lbpart)
{
  __shared__ int mw_lds[MW_RING * 512];  // per slot: 256 ints mask + 256 floats wgt

  const int bx = blockIdx.x;
  const int sp = bx % S, rb = bx / S;    // XCD-aligned splits (round-robin dispatch)
  const int n0 = rb * 16;
  const int mlen = 4096 / S;
  const int mc0 = (sp * mlen) >> 4;
  const int nch = mlen >> 4;             // 32 for S=8
  const int tid = threadIdx.x;
  const int lane = tid & 63, wvi = tid >> 6;  // 0..4

  if (wvi == 4) {
    // ---------- producer wave: deep async m/w staging, counted vmcnt ----------
    const int r = lane >> 2;
    const int qsw = ((lane & 3) + r) & 3;  // source-seg swizzle (consumer permutation)
    const int* msrc = msk + (size_t)(n0 + r) * 4096 + qsw * 4 + (size_t)mc0 * 16;
    const float* wsrc = wgt + (size_t)(n0 + r) * 4096 + qsw * 4 + (size_t)mc0 * 16;
#pragma unroll
    for (int d = 0; d < MW_D; ++d) {       // prologue: chunks 0..D-1 (14 loads)
      const int slot = d & (MW_RING - 1);
      __builtin_amdgcn_global_load_lds((gas_p)(msrc + (size_t)d * 16),
                                       (las_p)(&mw_lds[slot * 512]), 16, 0, 0);
      __builtin_amdgcn_global_load_lds((gas_p)(wsrc + (size_t)d * 16),
                                       (las_p)(&mw_lds[slot * 512 + 256]), 16, 0, 0);
    }
    for (int t = 0; t < nch; ++t) {
      // queue is ALWAYS 14 deep here -> vmcnt(12) retires exactly chunk t's 2 loads
      asm volatile("s_waitcnt vmcnt(12)" ::: "memory");
      __builtin_amdgcn_s_barrier();        // publish chunk t
      // ALWAYS issue (clamped source, raw slot): keeps queue depth constant so the
      // counted wait stays correct through the tail. Dead-slot writes race nothing:
      // that slot's last read completed before barrier t (consumer data-use).
      const int tn = t + MW_D;
      const int slot = tn & (MW_RING - 1);
      const size_t tsrc = (size_t)((tn < nch) ? tn : (nch - 1));
      __builtin_amdgcn_global_load_lds((gas_p)(msrc + tsrc * 16),
                                       (las_p)(&mw_lds[slot * 512]), 16, 0, 0);
      __builtin_amdgcn_global_load_lds((gas_p)(wsrc + tsrc * 16),
                                       (las_p)(&mw_lds[slot * 512 + 256]), 16, 0, 0);
    }
    return;
  }

  // ---------- 4 compute waves (head = wvi) ----------
  const int h = wvi;
  const int c = lane & 15, g = lane >> 4;

  bf16x8 qf[4];
#pragma unroll
  for (int ks = 0; ks < 4; ++ks)
    qf[ks] = *(const bf16x8*)(Qb + (size_t)(n0 + c) * 512 + h * 128 + ks * 32 + g * 8);

  f32x4 O[8];
#pragma unroll
  for (int db = 0; db < 8; ++db) O[db] = (f32x4)0.f;
  float lh = 0.f, lb = 0.f, ci = 0.f;

  const short* Kw = Kp + (size_t)h * 524288 + (size_t)lane * 8 + (size_t)mc0 * 2048;
  const short* Vw = Vp + (size_t)h * 524288 + (size_t)lane * 4 + (size_t)mc0 * 2048;
  // inverse of producer's source swizzle: row c, seg g lives at producer lane 4c+((g-c)&3)
  const int msel = (4 * c + ((g - c) & 3)) * 4;

  for (int t = 0; t < nch; ++t) {
    __builtin_amdgcn_s_barrier();          // chunk t staged (producer counted vmcnt)
    asm volatile("" ::: "memory");         // keep ds_read below the barrier
    const int slot = t & (MW_RING - 1);
    // K/V direct (vmcnt; L2-resident) — decoupled from m/w (lgkmcnt)
    bf16x8 kf[4];
#pragma unroll
    for (int ks = 0; ks < 4; ++ks)
      kf[ks] = *(const bf16x8*)(Kw + t * 2048 + ks * 512);
    bf16x4 vf[8];
#pragma unroll
    for (int db = 0; db < 8; ++db)
      vf[db] = *(const bf16x4*)(Vw + t * 2048 + db * 256);
    const int4 mkC = *(const int4*)&mw_lds[slot * 512 + msel];
    const f32x4 wvC = *(const f32x4*)((const float*)&mw_lds[slot * 512 + 256 + msel]);

    f32x4 Sv = (f32x4)0.f;
#pragma unroll
    for (int ks = 0; ks < 4; ++ks) Sv = MFMA32(kf[ks], qf[ks], Sv);
    const float e0 = mkC.x ? __expf(wvC.x) : 0.f;
    const float e1 = mkC.y ? __expf(wvC.y) : 0.f;
    const float e2 = mkC.z ? __expf(wvC.z) : 0.f;
    const float e3 = mkC.w ? __expf(wvC.w) : 0.f;
    const float p0 = __expf(Sv[0]) * e0, p1 = __expf(Sv[1]) * e1;
    const float p2 = __expf(Sv[2]) * e2, p3 = __expf(Sv[3]) * e3;
    lh += (p0 + p1) + (p2 + p3);
    lb += (e0 + e1) + (e2 + e3);
    ci += (p0 * e0 + p1 * e1) + (p2 * e2 + p3 * e3);
    bf16x4 pa;
    pa[0] = f2b(p0); pa[1] = f2b(p1); pa[2] = f2b(p2); pa[3] = f2b(p3);
#pragma unroll
    for (int db = 0; db < 8; ++db)
      O[db] = MFMA16(pa, vf[db], O[db]);
  }

  // reduce over g-groups (lanes ^16, ^32 share actor n=c)
  lh += __shfl_xor(lh, 16, 64); lh += __shfl_xor(lh, 32, 64);
  lb += __shfl_xor(lb, 16, 64); lb += __shfl_xor(lb, 32, 64);
  ci += __shfl_xor(ci, 16, 64); ci += __shfl_xor(ci, 32, 64);

  float inv[4];
#pragma unroll
  for (int r = 0; r < 4; ++r)
    inv[r] = 1.f / fmaxf(__shfl(lh, 4 * g + r, 64), 1e-30f);
#pragma unroll
  for (int db = 0; db < 8; ++db)
#pragma unroll
    for (int r = 0; r < 4; ++r)
      Opart[(size_t)sp * (4096 * 512) + (size_t)(n0 + g * 4 + r) * 512 +
            h * 128 + db * 16 + c] = f2b(O[db][r] * inv[r]);

  if (g == 0) {
    const int row = n0 + c;
    lpart[((size_t)sp * 4 + h) * 4096 + row] = lh;
    cipart[((size_t)sp * 4 + h) * 4096 + row] = ci;
    if (h == 0) lbpart[(size_t)sp * 4096 + row] = lb;
  }
}

// ---------------- K2b: combine splits ----------------
__global__ __launch_bounds__(256) void k_comb(
    const short* __restrict__ Opart, const float* __restrict__ lpart,
    const float* __restrict__ cipart, const float* __restrict__ lbpart,
    const int S, short* __restrict__ ctxb, float* __restrict__ validw,
    float* __restrict__ infl)
{
  const int tid = threadIdx.x;
  const int rloc = tid >> 5, cseg = tid & 31;
  const int row = blockIdx.x * 8 + rloc;
  const int col0 = cseg * 16;
  const int h = col0 >> 7;

  float l[4], ciS[4], lb = 0.f;
#pragma unroll
  for (int hh = 0; hh < 4; ++hh) { l[hh] = 0.f; ciS[hh] = 0.f; }
  for (int s = 0; s < S; ++s) {
#pragma unroll
    for (int hh = 0; hh < 4; ++hh) {
      l[hh]   += lpart[((size_t)s * 4 + hh) * 4096 + row];
      ciS[hh] += cipart[((size_t)s * 4 + hh) * 4096 + row];
    }
    lb += lbpart[(size_t)s * 4096 + row];
  }

  float acc[16];
#pragma unroll
  for (int j = 0; j < 16; ++j) acc[j] = 0.f;
  const float linv = 1.f / fmaxf(l[h], 1e-30f);
  for (int s = 0; s < S; ++s) {
    const float w_s = lpart[((size_t)s * 4 + h) * 4096 + row] * linv;
    const bf16x8 o0 = *(const bf16x8*)(Opart + (size_t)s * (4096 * 512) + (size_t)row * 512 + col0);
    const bf16x8 o1 = *(const bf16x8*)(Opart + (size_t)s * (4096 * 512) + (size_t)row * 512 + col0 + 8);
#pragma unroll
    for (int j = 0; j < 8; ++j) {
      union { unsigned u; float f; } v0, v1;
      v0.u = ((unsigned)(unsigned short)o0[j]) << 16;
      v1.u = ((unsigned)(unsigned short)o1[j]) << 16;
      acc[j]     += w_s * v0.f;
      acc[8 + j] += w_s * v1.f;
    }
  }
  bf16x8 c0, c1;
#pragma unroll
  for (int j = 0; j < 8; ++j) { c0[j] = f2b(acc[j]); c1[j] = f2b(acc[8 + j]); }
  *(bf16x8*)(ctxb + (size_t)row * 512 + col0) = c0;
  *(bf16x8*)(ctxb + (size_t)row * 512 + col0 + 8) = c1;

  if (cseg == 0) {
    validw[row] = (lb > 0.f) ? 1.f : 0.f;
    float s_ = 0.f;
#pragma unroll
    for (int hh = 0; hh < 4; ++hh) s_ += ciS[hh] / fmaxf(l[hh], 1e-30f);
    infl[row] = (lb > 0.f) ? s_ / (4.f * lb) : 0.f;
  }
}

// ---------------- K3: fold out_w over heads ----------------
__global__ void k_fold(const float* __restrict__ ow, const float* __restrict__ ob,
                       short* __restrict__ Wf, float* __restrict__ bfo)
{
  const int idx = blockIdx.x * 256 + threadIdx.x;
  if (idx < 128 * 512) {
    const int dk = idx >> 9, d = idx & 511;
    const float s = 0.25f * (ow[(size_t)dk * 512 + d] + ow[(size_t)(dk + 128) * 512 + d] +
                             ow[(size_t)(dk + 256) * 512 + d] + ow[(size_t)(dk + 384) * 512 + d]);
    Wf[(size_t)dk * 512 + d] = f2b(s);
  }
  if (idx < 128) bfo[idx] = 0.25f * (ob[idx] + ob[idx + 128] + ob[idx + 256] + ob[idx + 384]);
}

// ---------------- K4: topic = ctx @ Wfold^T + bfold (256 wgs, direct frags) ----------------
__global__ __launch_bounds__(256) void k_out(
    const short* __restrict__ ctxb, const short* __restrict__ Wf,
    const float* __restrict__ bfo, const float* __restrict__ validw,
    float* __restrict__ topic)
{
  const int tid = threadIdx.x;
  const int lane = tid & 63, wvi = tid >> 6;
  const int m0 = blockIdx.x * 16;
  const int c = lane & 15, g = lane >> 4;

  f32x4 acc[2];
  acc[0] = (f32x4)0.f; acc[1] = (f32x4)0.f;

  for (int k0 = 0; k0 < 512; k0 += 32) {
    const bf16x8 af = *(const bf16x8*)(ctxb + (size_t)(m0 + c) * 512 + k0 + g * 8);
#pragma unroll
    for (int dbl = 0; dbl < 2; ++dbl) {
      const bf16x8 bfr = *(const bf16x8*)(Wf + (size_t)(wvi * 32 + dbl * 16 + c) * 512 + k0 + g * 8);
      acc[dbl] = MFMA32(af, bfr, acc[dbl]);
    }
  }

#pragma unroll
  for (int r = 0; r < 4; ++r) {
    const int row = m0 + g * 4 + r;
    const float va = validw[row];
#pragma unroll
    for (int dbl = 0; dbl < 2; ++dbl) {
      const int col = wvi * 32 + dbl * 16 + c;
      const float vl = (va > 0.5f) ? (acc[dbl][r] + bfo[col]) : 0.f;
      topic[(size_t)row * 128 + col] = vl;
    }
  }
}

extern "C" void kernel_launch(void* const* d_in, const int* in_sizes, int n_in,
                              void* d_out, int out_size, void* d_ws, size_t ws_size,
                              hipStream_t stream) {
  const float* a_z  = (const float*)d_in[0];
  const float* bv_z = (const float*)d_in[1];
  const int*   mask = (const int*)d_in[2];
  const float* wgt  = (const float*)d_in[3];
  const float* ipw  = (const float*)d_in[4];
  const float* ipb  = (const float*)d_in[5];
  const float* ow   = (const float*)d_in[6];
  const float* ob   = (const float*)d_in[7];
  float* topic = (float*)d_out;              // [4096 x 128]
  float* infl  = (float*)d_out + 4096 * 128; // [4096]

  const size_t MB = (size_t)1 << 20;
  char* ws = (char*)d_ws;
  short* Qb     = (short*)(ws);                    // 4 MB
  short* Kp     = (short*)(ws + 4 * MB);           // 4 MB packed K frags
  short* Vp     = (short*)(ws + 8 * MB);           // 4 MB packed V frags
  short* ctxb   = (short*)(ws + 12 * MB);          // 4 MB
  float* validw = (float*)(ws + 16 * MB);          // 16 KB
  short* Wf     = (short*)(ws + 16 * MB + (64 << 10));   // 128 KB
  float* bfo    = (float*)(ws + 16 * MB + (224 << 10));  // 512 B
  const size_t pbase0 = 16 * MB + (256 << 10);

  // per split: Opart 4MB + lpart 64KB + cipart 64KB + lbpart 16KB
  auto need = [&](int S) { return pbase0 + (size_t)S * (4 * MB + (144 << 10)); };
  int S = 8;
  while (S > 1 && need(S) > ws_size) S >>= 1;

  char* pbase = ws + pbase0;
  short* Opart  = (short*)(pbase);
  float* lpart  = (float*)(pbase + (size_t)S * 4 * MB);
  float* cipart = (float*)(pbase + (size_t)S * 4 * MB + ((size_t)S << 16));
  float* lbpart = (float*)(pbase + (size_t)S * 4 * MB + ((size_t)S << 17));

  k_qkv <<<768, 256, 0, stream>>>(a_z, bv_z, ipw, ipb, Qb, Kp, Vp);
  k_fold<<<256, 256, 0, stream>>>(ow, ob, Wf, bfo);
  k_attn<<<256 * S, 320, 0, stream>>>(Qb, Kp, Vp, wgt, mask, S, Opart, lpart, cipart, lbpart);
  k_comb<<<512, 256, 0, stream>>>(Opart, lpart, cipart, lbpart, S, ctxb, validw, infl);
  k_out <<<256, 256, 0, stream>>>(ctxb, Wf, bfo, validw, topic);
}

// Round 15
// 330.430 us; speedup vs baseline: 1.2588x; 1.1233x over previous
//
#include <hip/hip_runtime.h>
#include <hip/hip_bf16.h>
#include <cstdint>
#include <cstddef>

// ActorHead fused pipeline, bf16 MFMA throughout.
//   K1 k_qkv : LDS-tiled GEMM-BT [4096x1536x512], 128x64 tiles (768 wgs)
//   K0 k_pre : E = mask ? exp(w) : 0 (f32), written in MFMA-lane order
//     Ep[rb][chunk][lane][4]. WHY: R0/R3/R11/R14 all ~1900cy/iter regardless of
//     prefetch depth/occupancy/producer-wave (R14: 14-deep producer = NULL).
//     The invariant: m/w loads gather 16B from 16 rows strided 16KB -> 64
//     DISTINCT cachelines per instruction; per-CU miss-tracking (~16 lines)
//     serializes each into ~4 HBM rounds (~3600cy) -> effective ~1 wave/SIMD
//     concurrency and the measured ~650GB/s closure. k_pre moves the gather
//     into a coalesced streaming pass; k_attn's m/w path becomes ONE coalesced
//     16B/lane load per iter (+ drops 4 exps + mask unpack from the loop).
//   K2 k_attn: split-K(S=8) flash attention, R3 structure (4 waves, no LDS),
//     sp = bx % S XCD-aligned splits (K/V 1MB L2-resident, FETCH 98MB, R3).
//     E depth-1 register prefetch (issued youngest -> rides vmcnt(1) on V-wait).
//     Fallback k_attn<0> = R3's mask/weight loop if Ep doesn't fit workspace.
//   K2b k_comb: merge splits; K3 k_fold; K4 k_out.
// d_out = topic[4096*128] fp32 ++ influence[4096] fp32

typedef __attribute__((ext_vector_type(8))) short bf16x8;
typedef __attribute__((ext_vector_type(4))) short bf16x4;
typedef __attribute__((ext_vector_type(4))) float f32x4;

#define MFMA32(a, b, c) __builtin_amdgcn_mfma_f32_16x16x32_bf16((a), (b), (c), 0, 0, 0)
#define MFMA16(a, b, c) __builtin_amdgcn_mfma_f32_16x16x16bf16_1k((a), (b), (c), 0, 0, 0)

static __device__ __forceinline__ short f2b(float x) {
  union { float f; unsigned u; } v; v.f = x;
  unsigned r = v.u + 0x7fffu + ((v.u >> 16) & 1u);  // RNE to bf16
  return (short)(r >> 16);
}

// ---------------- K1: QKV projection (LDS-tiled 128x64, packed epilogue) ----------------
__global__ __launch_bounds__(256) void k_qkv(
    const float* __restrict__ a, const float* __restrict__ kv,
    const float* __restrict__ w, const float* __restrict__ bias,
    short* __restrict__ Qb, short* __restrict__ Kp, short* __restrict__ Vp)
{
  __shared__ short As[128 * 40];
  __shared__ short Bs[64 * 40];
  const int blk = blockIdx.x;
  const int bm = blk % 32, bn = blk / 32;
  const int m0 = bm * 128, n0 = bn * 64;
  const float* __restrict__ Ain = (bn < 8) ? a : kv;
  const int tid = threadIdx.x;
  const int lane = tid & 63, wvi = tid >> 6;
  const int wm = (wvi >> 1) * 64, wn = (wvi & 1) * 32;
  const int c = lane & 15, g = lane >> 4;
  const int srA = tid >> 1, scA = (tid & 1) * 16;
  const int srB = tid >> 2, scB = (tid & 3) * 8;

  f32x4 acc[4][2];
#pragma unroll
  for (int i = 0; i < 4; ++i)
#pragma unroll
    for (int j = 0; j < 2; ++j) acc[i][j] = (f32x4)0.f;

  for (int k0 = 0; k0 < 512; k0 += 32) {
    const float* ap = Ain + (size_t)(m0 + srA) * 512 + k0 + scA;
#pragma unroll
    for (int j = 0; j < 4; ++j) {
      f32x4 av = *(const f32x4*)(ap + 4 * j);
      bf16x4 as;
      as.x = f2b(av.x); as.y = f2b(av.y); as.z = f2b(av.z); as.w = f2b(av.w);
      *(bf16x4*)(&As[srA * 40 + scA + 4 * j]) = as;
    }
    const float* bp = w + (size_t)(n0 + srB) * 512 + k0 + scB;
#pragma unroll
    for (int j = 0; j < 2; ++j) {
      f32x4 bv = *(const f32x4*)(bp + 4 * j);
      bf16x4 bs;
      bs.x = f2b(bv.x); bs.y = f2b(bv.y); bs.z = f2b(bv.z); bs.w = f2b(bv.w);
      *(bf16x4*)(&Bs[srB * 40 + scB + 4 * j]) = bs;
    }
    __syncthreads();
    bf16x8 af[4], bfg[2];
#pragma unroll
    for (int t = 0; t < 4; ++t)
      af[t] = *(const bf16x8*)(&As[(wm + t * 16 + c) * 40 + g * 8]);
#pragma unroll
    for (int t = 0; t < 2; ++t)
      bfg[t] = *(const bf16x8*)(&Bs[(wn + t * 16 + c) * 40 + g * 8]);
#pragma unroll
    for (int rt = 0; rt < 4; ++rt)
#pragma unroll
      for (int ct = 0; ct < 2; ++ct)
        acc[rt][ct] = MFMA32(af[rt], bfg[ct], acc[rt][ct]);
    __syncthreads();
  }

#pragma unroll
  for (int ct = 0; ct < 2; ++ct) {
    const int col = n0 + wn + ct * 16 + c;
    const float bj = bias[col];
#pragma unroll
    for (int rt = 0; rt < 4; ++rt) {
      const int row = m0 + wm + rt * 16 + g * 4;
      const int mc = row >> 4;
      if (col < 512) {
#pragma unroll
        for (int r = 0; r < 4; ++r)
          Qb[(size_t)(row + r) * 512 + col] = f2b((acc[rt][ct][r] + bj) * 0.08838834764831843f);
      } else if (col < 1024) {
        const int colK = col - 512;
        const int h = colK >> 7, dk = colK & 127;
        const int ks = dk >> 5, gk = (dk >> 3) & 3, j = dk & 7;
        short* base = Kp + (size_t)((((h * 256 + mc) * 4 + ks) * 64) + gk * 16 + g * 4) * 8 + j;
#pragma unroll
        for (int r = 0; r < 4; ++r) base[r * 8] = f2b(acc[rt][ct][r] + bj);
      } else {
        const int colV = col - 1024;
        const int h = colV >> 7, db = (colV & 127) >> 4, cv = colV & 15;
        bf16x4 pk;
#pragma unroll
        for (int r = 0; r < 4; ++r) pk[r] = f2b(acc[rt][ct][r] + bj);
        *(bf16x4*)(Vp + (size_t)((((h * 256 + mc) * 8 + db) * 64) + g * 16 + cv) * 4) = pk;
      }
    }
  }
}

// ---------------- K0: E = mask ? exp(w) : 0, in MFMA-lane order ----------------
// Ep flat f32 index: ((rb*256 + mc)*64 + g*16 + c)*4 + r  for row rb*16+c,
// key mc*16 + g*4 + r. 2048 blocks x 256 thr: block b -> rb=b>>3, key-slice b&7.
__global__ __launch_bounds__(256) void k_pre(
    const int* __restrict__ msk, const float* __restrict__ wgt,
    float* __restrict__ Ep)
{
  const int b = blockIdx.x;
  const int rb = b >> 3, ks8 = b & 7;
  const int t = threadIdx.x;
  const int c = t >> 4;               // row within rb
  const int row = rb * 16 + c;
  const int lt = t & 15;
  const int g = t & 3;
#pragma unroll
  for (int p = 0; p < 8; ++p) {
    const int k0 = ks8 * 512 + p * 64 + lt * 4;   // 4 keys, same chunk
    const int4 mk = *(const int4*)(msk + (size_t)row * 4096 + k0);
    const f32x4 wv = *(const f32x4*)(wgt + (size_t)row * 4096 + k0);
    f32x4 ev;
    ev[0] = mk.x ? __expf(wv.x) : 0.f;
    ev[1] = mk.y ? __expf(wv.y) : 0.f;
    ev[2] = mk.z ? __expf(wv.z) : 0.f;
    ev[3] = mk.w ? __expf(wv.w) : 0.f;
    const int mc = k0 >> 4;
    *(f32x4*)(Ep + ((size_t)(rb * 256 + mc) * 64 + g * 16 + c) * 4) = ev;
  }
}

// ---------------- K2: split-K flash attention ----------------
template<int EP>
__global__ __launch_bounds__(256, 4) void k_attn(
    const short* __restrict__ Qb, const short* __restrict__ Kp,
    const short* __restrict__ Vp, const float* __restrict__ wgt,
    const int* __restrict__ msk, const int S,
    short* __restrict__ Opart, float* __restrict__ lpart,
    float* __restrict__ cipart, float* __restrict__ lbpart,
    const float* __restrict__ Ep)
{
  const int bx = blockIdx.x;
  // sp = bx % S: round-robin block->XCD dispatch -> one split per XCD (K/V 1MB L2).
  const int sp = bx % S, rb = bx / S;
  const int n0 = rb * 16;
  const int mlen = 4096 / S;
  const int mc0 = (sp * mlen) >> 4;
  const int nch = mlen >> 4;
  const int tid = threadIdx.x;
  const int lane = tid & 63, h = tid >> 6;
  const int c = lane & 15, g = lane >> 4;

  bf16x8 qf[4];
#pragma unroll
  for (int ks = 0; ks < 4; ++ks)
    qf[ks] = *(const bf16x8*)(Qb + (size_t)(n0 + c) * 512 + h * 128 + ks * 32 + g * 8);

  f32x4 O[8];
#pragma unroll
  for (int db = 0; db < 8; ++db) O[db] = (f32x4)0.f;
  float lh = 0.f, lb = 0.f, ci = 0.f;

  const short* Kw = Kp + (size_t)h * 524288 + (size_t)lane * 8 + (size_t)mc0 * 2048;
  const short* Vw = Vp + (size_t)h * 524288 + (size_t)lane * 4 + (size_t)mc0 * 2048;

  if (EP) {
    // -------- coalesced E-table path: one 16B/lane load per chunk --------
    const float* Eb = Ep + ((size_t)(rb * 256 + mc0) * 64 + lane) * 4;
    f32x4 evC = *(const f32x4*)(Eb);   // chunk 0
    for (int t = 0; t < nch; ++t) {
      bf16x8 kf[4];
#pragma unroll
      for (int ks = 0; ks < 4; ++ks)
        kf[ks] = *(const bf16x8*)(Kw + t * 2048 + ks * 512);
      bf16x4 vf[8];
#pragma unroll
      for (int db = 0; db < 8; ++db)
        vf[db] = *(const bf16x4*)(Vw + t * 2048 + db * 256);
      const f32x4 ev = evC;
      const int tn = (t + 1 < nch) ? (t + 1) : t;
      evC = *(const f32x4*)(Eb + (size_t)tn * 256);  // youngest: in flight across K/V waits

      f32x4 Sa = (f32x4)0.f, Sb = (f32x4)0.f;
      Sa = MFMA32(kf[0], qf[0], Sa);
      Sb = MFMA32(kf[2], qf[2], Sb);
      Sa = MFMA32(kf[1], qf[1], Sa);
      Sb = MFMA32(kf[3], qf[3], Sb);
      const float p0 = __expf(Sa[0] + Sb[0]) * ev[0];
      const float p1 = __expf(Sa[1] + Sb[1]) * ev[1];
      const float p2 = __expf(Sa[2] + Sb[2]) * ev[2];
      const float p3 = __expf(Sa[3] + Sb[3]) * ev[3];
      lh += (p0 + p1) + (p2 + p3);
      lb += (ev[0] + ev[1]) + (ev[2] + ev[3]);
      ci += (p0 * ev[0] + p1 * ev[1]) + (p2 * ev[2] + p3 * ev[3]);
      bf16x4 pa;
      pa[0] = f2b(p0); pa[1] = f2b(p1); pa[2] = f2b(p2); pa[3] = f2b(p3);
#pragma unroll
      for (int db = 0; db < 8; ++db)
        O[db] = MFMA16(pa, vf[db], O[db]);
    }
  } else {
    // -------- fallback: R3's direct mask/weight loop (196us baseline) --------
    const int* mbase_p = msk + (size_t)(n0 + c) * 4096 + g * 4 + (size_t)mc0 * 16;
    const float* wbase_p = wgt + (size_t)(n0 + c) * 4096 + g * 4 + (size_t)mc0 * 16;
    int4 mkN = *(const int4*)(mbase_p);
    f32x4 wvN = *(const f32x4*)(wbase_p);
    for (int t = 0; t < nch; ++t) {
      bf16x8 kf[4];
#pragma unroll
      for (int ks = 0; ks < 4; ++ks)
        kf[ks] = *(const bf16x8*)(Kw + t * 2048 + ks * 512);
      bf16x4 vf[8];
#pragma unroll
      for (int db = 0; db < 8; ++db)
        vf[db] = *(const bf16x4*)(Vw + t * 2048 + db * 256);
      const int4 mkC = mkN;
      const f32x4 wvC = wvN;
      const int tn = (t + 1 < nch) ? (t + 1) : t;
      mkN = *(const int4*)(mbase_p + tn * 16);
      wvN = *(const f32x4*)(wbase_p + tn * 16);
      f32x4 Sv = (f32x4)0.f;
#pragma unroll
      for (int ks = 0; ks < 4; ++ks) Sv = MFMA32(kf[ks], qf[ks], Sv);
      const float e0 = mkC.x ? __expf(wvC.x) : 0.f;
      const float e1 = mkC.y ? __expf(wvC.y) : 0.f;
      const float e2 = mkC.z ? __expf(wvC.z) : 0.f;
      const float e3 = mkC.w ? __expf(wvC.w) : 0.f;
      const float p0 = __expf(Sv[0]) * e0, p1 = __expf(Sv[1]) * e1;
      const float p2 = __expf(Sv[2]) * e2, p3 = __expf(Sv[3]) * e3;
      lh += (p0 + p1) + (p2 + p3);
      lb += (e0 + e1) + (e2 + e3);
      ci += (p0 * e0 + p1 * e1) + (p2 * e2 + p3 * e3);
      bf16x4 pa;
      pa[0] = f2b(p0); pa[1] = f2b(p1); pa[2] = f2b(p2); pa[3] = f2b(p3);
#pragma unroll
      for (int db = 0; db < 8; ++db)
        O[db] = MFMA16(pa, vf[db], O[db]);
    }
  }

  // reduce over g-groups (lanes ^16, ^32 share actor n=c)
  lh += __shfl_xor(lh, 16, 64); lh += __shfl_xor(lh, 32, 64);
  lb += __shfl_xor(lb, 16, 64); lb += __shfl_xor(lb, 32, 64);
  ci += __shfl_xor(ci, 16, 64); ci += __shfl_xor(ci, 32, 64);

  float inv[4];
#pragma unroll
  for (int r = 0; r < 4; ++r)
    inv[r] = 1.f / fmaxf(__shfl(lh, 4 * g + r, 64), 1e-30f);
#pragma unroll
  for (int db = 0; db < 8; ++db)
#pragma unroll
    for (int r = 0; r < 4; ++r)
      Opart[(size_t)sp * (4096 * 512) + (size_t)(n0 + g * 4 + r) * 512 +
            h * 128 + db * 16 + c] = f2b(O[db][r] * inv[r]);

  if (g == 0) {
    const int row = n0 + c;
    lpart[((size_t)sp * 4 + h) * 4096 + row] = lh;
    cipart[((size_t)sp * 4 + h) * 4096 + row] = ci;
    if (h == 0) lbpart[(size_t)sp * 4096 + row] = lb;
  }
}

// ---------------- K2b: combine splits ----------------
__global__ __launch_bounds__(256) void k_comb(
    const short* __restrict__ Opart, const float* __restrict__ lpart,
    const float* __restrict__ cipart, const float* __restrict__ lbpart,
    const int S, short* __restrict__ ctxb, float* __restrict__ validw,
    float* __restrict__ infl)
{
  const int tid = threadIdx.x;
  const int rloc = tid >> 5, cseg = tid & 31;
  const int row = blockIdx.x * 8 + rloc;
  const int col0 = cseg * 16;
  const int h = col0 >> 7;

  float l[4], ciS[4], lb = 0.f;
#pragma unroll
  for (int hh = 0; hh < 4; ++hh) { l[hh] = 0.f; ciS[hh] = 0.f; }
  for (int s = 0; s < S; ++s) {
#pragma unroll
    for (int hh = 0; hh < 4; ++hh) {
      l[hh]   += lpart[((size_t)s * 4 + hh) * 4096 + row];
      ciS[hh] += cipart[((size_t)s * 4 + hh) * 4096 + row];
    }
    lb += lbpart[(size_t)s * 4096 + row];
  }

  float acc[16];
#pragma unroll
  for (int j = 0; j < 16; ++j) acc[j] = 0.f;
  const float linv = 1.f / fmaxf(l[h], 1e-30f);
  for (int s = 0; s < S; ++s) {
    const float w_s = lpart[((size_t)s * 4 + h) * 4096 + row] * linv;
    const bf16x8 o0 = *(const bf16x8*)(Opart + (size_t)s * (4096 * 512) + (size_t)row * 512 + col0);
    const bf16x8 o1 = *(const bf16x8*)(Opart + (size_t)s * (4096 * 512) + (size_t)row * 512 + col0 + 8);
#pragma unroll
    for (int j = 0; j < 8; ++j) {
      union { unsigned u; float f; } v0, v1;
      v0.u = ((unsigned)(unsigned short)o0[j]) << 16;
      v1.u = ((unsigned)(unsigned short)o1[j]) << 16;
      acc[j]     += w_s * v0.f;
      acc[8 + j] += w_s * v1.f;
    }
  }
  bf16x8 c0, c1;
#pragma unroll
  for (int j = 0; j < 8; ++j) { c0[j] = f2b(acc[j]); c1[j] = f2b(acc[8 + j]); }
  *(bf16x8*)(ctxb + (size_t)row * 512 + col0) = c0;
  *(bf16x8*)(ctxb + (size_t)row * 512 + col0 + 8) = c1;

  if (cseg == 0) {
    validw[row] = (lb > 0.f) ? 1.f : 0.f;
    float s_ = 0.f;
#pragma unroll
    for (int hh = 0; hh < 4; ++hh) s_ += ciS[hh] / fmaxf(l[hh], 1e-30f);
    infl[row] = (lb > 0.f) ? s_ / (4.f * lb) : 0.f;
  }
}

// ---------------- K3: fold out_w over heads ----------------
__global__ void k_fold(const float* __restrict__ ow, const float* __restrict__ ob,
                       short* __restrict__ Wf, float* __restrict__ bfo)
{
  const int idx = blockIdx.x * 256 + threadIdx.x;
  if (idx < 128 * 512) {
    const int dk = idx >> 9, d = idx & 511;
    const float s = 0.25f * (ow[(size_t)dk * 512 + d] + ow[(size_t)(dk + 128) * 512 + d] +
                             ow[(size_t)(dk + 256) * 512 + d] + ow[(size_t)(dk + 384) * 512 + d]);
    Wf[(size_t)dk * 512 + d] = f2b(s);
  }
  if (idx < 128) bfo[idx] = 0.25f * (ob[idx] + ob[idx + 128] + ob[idx + 256] + ob[idx + 384]);
}

// ---------------- K4: topic = ctx @ Wfold^T + bfold (256 wgs, direct frags) ----------------
__global__ __launch_bounds__(256) void k_out(
    const short* __restrict__ ctxb, const short* __restrict__ Wf,
    const float* __restrict__ bfo, const float* __restrict__ validw,
    float* __restrict__ topic)
{
  const int tid = threadIdx.x;
  const int lane = tid & 63, wvi = tid >> 6;
  const int m0 = blockIdx.x * 16;
  const int c = lane & 15, g = lane >> 4;

  f32x4 acc[2];
  acc[0] = (f32x4)0.f; acc[1] = (f32x4)0.f;

  for (int k0 = 0; k0 < 512; k0 += 32) {
    const bf16x8 af = *(const bf16x8*)(ctxb + (size_t)(m0 + c) * 512 + k0 + g * 8);
#pragma unroll
    for (int dbl = 0; dbl < 2; ++dbl) {
      const bf16x8 bfr = *(const bf16x8*)(Wf + (size_t)(wvi * 32 + dbl * 16 + c) * 512 + k0 + g * 8);
      acc[dbl] = MFMA32(af, bfr, acc[dbl]);
    }
  }

#pragma unroll
  for (int r = 0; r < 4; ++r) {
    const int row = m0 + g * 4 + r;
    const float va = validw[row];
#pragma unroll
    for (int dbl = 0; dbl < 2; ++dbl) {
      const int col = wvi * 32 + dbl * 16 + c;
      const float vl = (va > 0.5f) ? (acc[dbl][r] + bfo[col]) : 0.f;
      topic[(size_t)row * 128 + col] = vl;
    }
  }
}

extern "C" void kernel_launch(void* const* d_in, const int* in_sizes, int n_in,
                              void* d_out, int out_size, void* d_ws, size_t ws_size,
                              hipStream_t stream) {
  const float* a_z  = (const float*)d_in[0];
  const float* bv_z = (const float*)d_in[1];
  const int*   mask = (const int*)d_in[2];
  const float* wgt  = (const float*)d_in[3];
  const float* ipw  = (const float*)d_in[4];
  const float* ipb  = (const float*)d_in[5];
  const float* ow   = (const float*)d_in[6];
  const float* ob   = (const float*)d_in[7];
  float* topic = (float*)d_out;              // [4096 x 128]
  float* infl  = (float*)d_out + 4096 * 128; // [4096]

  const size_t MB = (size_t)1 << 20;
  char* ws = (char*)d_ws;
  short* Qb     = (short*)(ws);                    // 4 MB
  short* Kp     = (short*)(ws + 4 * MB);           // 4 MB packed K frags
  short* Vp     = (short*)(ws + 8 * MB);           // 4 MB packed V frags
  short* ctxb   = (short*)(ws + 12 * MB);          // 4 MB
  float* validw = (float*)(ws + 16 * MB);          // 16 KB
  short* Wf     = (short*)(ws + 16 * MB + (64 << 10));   // 128 KB
  float* bfo    = (float*)(ws + 16 * MB + (224 << 10));  // 512 B
  const size_t fixed = 16 * MB + (256 << 10);
  const size_t epBytes = (size_t)4096 * 4096 * 4;        // 64 MiB f32 E-table

  // per split: Opart 4MB + lpart 64KB + cipart 64KB + lbpart 16KB
  auto need = [&](int S, int ep) {
    return fixed + (ep ? epBytes : 0) + (size_t)S * (4 * MB + (144 << 10));
  };
  int S = 8, useEp = 1;
  while (S > 1 && need(S, 1) > ws_size) S >>= 1;
  if (need(S, 1) > ws_size) {            // Ep doesn't fit even at S=1: old path
    useEp = 0; S = 8;
    while (S > 1 && need(S, 0) > ws_size) S >>= 1;
  }
  float* Ep = useEp ? (float*)(ws + fixed) : nullptr;
  char* pbase = ws + fixed + (useEp ? epBytes : 0);
  short* Opart  = (short*)(pbase);
  float* lpart  = (float*)(pbase + (size_t)S * 4 * MB);
  float* cipart = (float*)(pbase + (size_t)S * 4 * MB + ((size_t)S << 16));
  float* lbpart = (float*)(pbase + (size_t)S * 4 * MB + ((size_t)S << 17));

  k_qkv <<<768, 256, 0, stream>>>(a_z, bv_z, ipw, ipb, Qb, Kp, Vp);
  k_fold<<<256, 256, 0, stream>>>(ow, ob, Wf, bfo);
  if (useEp) {
    k_pre<<<2048, 256, 0, stream>>>(mask, wgt, Ep);
    k_attn<1><<<256 * S, 256, 0, stream>>>(Qb, Kp, Vp, wgt, mask, S,
                                           Opart, lpart, cipart, lbpart, Ep);
  } else {
    k_attn<0><<<256 * S, 256, 0, stream>>>(Qb, Kp, Vp, wgt, mask, S,
                                           Opart, lpart, cipart, lbpart, Ep);
  }
  k_comb<<<512, 256, 0, stream>>>(Opart, lpart, cipart, lbpart, S, ctxb, validw, infl);
  k_out <<<256, 256, 0, stream>>>(ctxb, Wf, bfo, validw, topic);
}

// Round 16
// 322.378 us; speedup vs baseline: 1.2902x; 1.0250x over previous
//
#include <hip/hip_runtime.h>
#include <hip/hip_bf16.h>
#include <cstdint>
#include <cstddef>

// ActorHead fused pipeline, bf16 MFMA throughout.
//   K0 k_front: MERGED front-end (one launch, blocks branch):
//     [0,768)    qkv: LDS-tiled GEMM-BT [4096x1536x512], 128x64 tiles
//     [768,2816) pre: E = mask ? exp(w) : 0 (f32) in MFMA-lane order
//                Ep[rb][chunk][lane][4] — R15 confirmed: coalescing the m/w
//                gather (64 lines/instr -> 16) cut k_attn 196->123us.
//     [2816,3072) fold: out_w head-fold
//     Merging overlaps the ~45us bandwidth-bound pre under the compute-bound
//     qkv (stream otherwise serializes them).
//   K2 k_attn: split-K(S=8) flash attention, R3 structure + E-table path +
//     K DEPTH-1 REGISTER PREFETCH (unroll-2, named kA/kB): K comes from L2
//     (~250cy) and was consumed ~30cy after issue — the E-table freed the
//     mask/weight regs that made R4's version spill (est ~104 unified < 128).
//     V stays in-iteration: V's wait doesn't retire the younger K(t+1)/E loads.
//     sp = bx % S XCD-aligned splits (K/V 1MB L2-resident, R3).
//   K2b k_comb: merge splits; K4 k_out.
// d_out = topic[4096*128] fp32 ++ influence[4096] fp32

typedef __attribute__((ext_vector_type(8))) short bf16x8;
typedef __attribute__((ext_vector_type(4))) short bf16x4;
typedef __attribute__((ext_vector_type(4))) float f32x4;

#define MFMA32(a, b, c) __builtin_amdgcn_mfma_f32_16x16x32_bf16((a), (b), (c), 0, 0, 0)
#define MFMA16(a, b, c) __builtin_amdgcn_mfma_f32_16x16x16bf16_1k((a), (b), (c), 0, 0, 0)

static __device__ __forceinline__ short f2b(float x) {
  union { float f; unsigned u; } v; v.f = x;
  unsigned r = v.u + 0x7fffu + ((v.u >> 16) & 1u);  // RNE to bf16
  return (short)(r >> 16);
}

// ---------------- K0: merged front-end ----------------
__global__ __launch_bounds__(256) void k_front(
    const float* __restrict__ a, const float* __restrict__ kv,
    const float* __restrict__ w, const float* __restrict__ bias,
    short* __restrict__ Qb, short* __restrict__ Kp, short* __restrict__ Vp,
    const int* __restrict__ msk, const float* __restrict__ wgt,
    float* __restrict__ Ep,
    const float* __restrict__ ow, const float* __restrict__ ob,
    short* __restrict__ Wf, float* __restrict__ bfo, const int useEp)
{
  __shared__ short As[128 * 40];
  __shared__ short Bs[64 * 40];
  const int blk = blockIdx.x;
  const int tid = threadIdx.x;

  if (blk < 768) {
    // -------- qkv GEMM --------
    const int bm = blk % 32, bn = blk / 32;
    const int m0 = bm * 128, n0 = bn * 64;
    const float* __restrict__ Ain = (bn < 8) ? a : kv;
    const int lane = tid & 63, wvi = tid >> 6;
    const int wm = (wvi >> 1) * 64, wn = (wvi & 1) * 32;
    const int c = lane & 15, g = lane >> 4;
    const int srA = tid >> 1, scA = (tid & 1) * 16;
    const int srB = tid >> 2, scB = (tid & 3) * 8;

    f32x4 acc[4][2];
#pragma unroll
    for (int i = 0; i < 4; ++i)
#pragma unroll
      for (int j = 0; j < 2; ++j) acc[i][j] = (f32x4)0.f;

    for (int k0 = 0; k0 < 512; k0 += 32) {
      const float* ap = Ain + (size_t)(m0 + srA) * 512 + k0 + scA;
#pragma unroll
      for (int j = 0; j < 4; ++j) {
        f32x4 av = *(const f32x4*)(ap + 4 * j);
        bf16x4 as;
        as.x = f2b(av.x); as.y = f2b(av.y); as.z = f2b(av.z); as.w = f2b(av.w);
        *(bf16x4*)(&As[srA * 40 + scA + 4 * j]) = as;
      }
      const float* bp = w + (size_t)(n0 + srB) * 512 + k0 + scB;
#pragma unroll
      for (int j = 0; j < 2; ++j) {
        f32x4 bv = *(const f32x4*)(bp + 4 * j);
        bf16x4 bs;
        bs.x = f2b(bv.x); bs.y = f2b(bv.y); bs.z = f2b(bv.z); bs.w = f2b(bv.w);
        *(bf16x4*)(&Bs[srB * 40 + scB + 4 * j]) = bs;
      }
      __syncthreads();
      bf16x8 af[4], bfg[2];
#pragma unroll
      for (int t = 0; t < 4; ++t)
        af[t] = *(const bf16x8*)(&As[(wm + t * 16 + c) * 40 + g * 8]);
#pragma unroll
      for (int t = 0; t < 2; ++t)
        bfg[t] = *(const bf16x8*)(&Bs[(wn + t * 16 + c) * 40 + g * 8]);
#pragma unroll
      for (int rt = 0; rt < 4; ++rt)
#pragma unroll
        for (int ct = 0; ct < 2; ++ct)
          acc[rt][ct] = MFMA32(af[rt], bfg[ct], acc[rt][ct]);
      __syncthreads();
    }

#pragma unroll
    for (int ct = 0; ct < 2; ++ct) {
      const int col = n0 + wn + ct * 16 + c;
      const float bj = bias[col];
#pragma unroll
      for (int rt = 0; rt < 4; ++rt) {
        const int row = m0 + wm + rt * 16 + g * 4;
        const int mc = row >> 4;
        if (col < 512) {
#pragma unroll
          for (int r = 0; r < 4; ++r)
            Qb[(size_t)(row + r) * 512 + col] = f2b((acc[rt][ct][r] + bj) * 0.08838834764831843f);
        } else if (col < 1024) {
          const int colK = col - 512;
          const int h = colK >> 7, dk = colK & 127;
          const int ks = dk >> 5, gk = (dk >> 3) & 3, j = dk & 7;
          short* base = Kp + (size_t)((((h * 256 + mc) * 4 + ks) * 64) + gk * 16 + g * 4) * 8 + j;
#pragma unroll
          for (int r = 0; r < 4; ++r) base[r * 8] = f2b(acc[rt][ct][r] + bj);
        } else {
          const int colV = col - 1024;
          const int h = colV >> 7, db = (colV & 127) >> 4, cv = colV & 15;
          bf16x4 pk;
#pragma unroll
          for (int r = 0; r < 4; ++r) pk[r] = f2b(acc[rt][ct][r] + bj);
          *(bf16x4*)(Vp + (size_t)((((h * 256 + mc) * 8 + db) * 64) + g * 16 + cv) * 4) = pk;
        }
      }
    }
  } else if (blk < 2816) {
    // -------- pre: E-table (coalesced stream) --------
    if (!useEp) return;
    const int b = blk - 768;
    const int rb = b >> 3, ks8 = b & 7;
    const int c = tid >> 4;
    const int row = rb * 16 + c;
    const int lt = tid & 15;
    const int g = tid & 3;
#pragma unroll
    for (int p = 0; p < 8; ++p) {
      const int k0 = ks8 * 512 + p * 64 + lt * 4;
      const int4 mk = *(const int4*)(msk + (size_t)row * 4096 + k0);
      const f32x4 wv = *(const f32x4*)(wgt + (size_t)row * 4096 + k0);
      f32x4 ev;
      ev[0] = mk.x ? __expf(wv.x) : 0.f;
      ev[1] = mk.y ? __expf(wv.y) : 0.f;
      ev[2] = mk.z ? __expf(wv.z) : 0.f;
      ev[3] = mk.w ? __expf(wv.w) : 0.f;
      const int mc = k0 >> 4;
      *(f32x4*)(Ep + ((size_t)(rb * 256 + mc) * 64 + g * 16 + c) * 4) = ev;
    }
  } else {
    // -------- fold out_w over heads --------
    const int idx = (blk - 2816) * 256 + tid;
    if (idx < 128 * 512) {
      const int dk = idx >> 9, d = idx & 511;
      const float s = 0.25f * (ow[(size_t)dk * 512 + d] + ow[(size_t)(dk + 128) * 512 + d] +
                               ow[(size_t)(dk + 256) * 512 + d] + ow[(size_t)(dk + 384) * 512 + d]);
      Wf[(size_t)dk * 512 + d] = f2b(s);
    }
    if (idx < 128) bfo[idx] = 0.25f * (ob[idx] + ob[idx + 128] + ob[idx + 256] + ob[idx + 384]);
  }
}

// ---------------- K2: split-K flash attention ----------------
// One chunk: issue V(TT) (oldest), rotate E, prefetch E(TN) and K(TN) (youngest,
// ride across V's wait), compute with KC (loaded last iteration, ~1 iter flight).
#define ASTEP(TT, KC, KN, TN)                                                  \
  do {                                                                         \
    bf16x4 vf[8];                                                              \
    _Pragma("unroll")                                                          \
    for (int db = 0; db < 8; ++db)                                             \
      vf[db] = *(const bf16x4*)(Vw + (TT) * 2048 + db * 256);                  \
    const f32x4 ev = evC;                                                      \
    evC = *(const f32x4*)(Eb + (size_t)(TN) * 256);                            \
    _Pragma("unroll")                                                          \
    for (int ks = 0; ks < 4; ++ks)                                             \
      KN[ks] = *(const bf16x8*)(Kw + (TN) * 2048 + ks * 512);                  \
    f32x4 Sa = (f32x4)0.f, Sb = (f32x4)0.f;                                    \
    Sa = MFMA32(KC[0], qf[0], Sa);                                             \
    Sb = MFMA32(KC[2], qf[2], Sb);                                             \
    Sa = MFMA32(KC[1], qf[1], Sa);                                             \
    Sb = MFMA32(KC[3], qf[3], Sb);                                             \
    const float p0 = __expf(Sa[0] + Sb[0]) * ev[0];                            \
    const float p1 = __expf(Sa[1] + Sb[1]) * ev[1];                            \
    const float p2 = __expf(Sa[2] + Sb[2]) * ev[2];                            \
    const float p3 = __expf(Sa[3] + Sb[3]) * ev[3];                            \
    lh += (p0 + p1) + (p2 + p3);                                               \
    lb += (ev[0] + ev[1]) + (ev[2] + ev[3]);                                   \
    ci += (p0 * ev[0] + p1 * ev[1]) + (p2 * ev[2] + p3 * ev[3]);               \
    bf16x4 pa;                                                                 \
    pa[0] = f2b(p0); pa[1] = f2b(p1); pa[2] = f2b(p2); pa[3] = f2b(p3);        \
    _Pragma("unroll")                                                          \
    for (int db = 0; db < 8; ++db)                                             \
      O[db] = MFMA16(pa, vf[db], O[db]);                                       \
  } while (0)

template<int EP>
__global__ __launch_bounds__(256, 4) void k_attn(
    const short* __restrict__ Qb, const short* __restrict__ Kp,
    const short* __restrict__ Vp, const float* __restrict__ wgt,
    const int* __restrict__ msk, const int S,
    short* __restrict__ Opart, float* __restrict__ lpart,
    float* __restrict__ cipart, float* __restrict__ lbpart,
    const float* __restrict__ Ep)
{
  const int bx = blockIdx.x;
  // sp = bx % S: round-robin block->XCD dispatch -> one split per XCD (K/V 1MB L2).
  const int sp = bx % S, rb = bx / S;
  const int n0 = rb * 16;
  const int mlen = 4096 / S;
  const int mc0 = (sp * mlen) >> 4;
  const int nch = mlen >> 4;   // 32 for S=8; even for S in {1,2,4,8}
  const int tid = threadIdx.x;
  const int lane = tid & 63, h = tid >> 6;
  const int c = lane & 15, g = lane >> 4;

  bf16x8 qf[4];
#pragma unroll
  for (int ks = 0; ks < 4; ++ks)
    qf[ks] = *(const bf16x8*)(Qb + (size_t)(n0 + c) * 512 + h * 128 + ks * 32 + g * 8);

  f32x4 O[8];
#pragma unroll
  for (int db = 0; db < 8; ++db) O[db] = (f32x4)0.f;
  float lh = 0.f, lb = 0.f, ci = 0.f;

  const short* Kw = Kp + (size_t)h * 524288 + (size_t)lane * 8 + (size_t)mc0 * 2048;
  const short* Vw = Vp + (size_t)h * 524288 + (size_t)lane * 4 + (size_t)mc0 * 2048;

  if (EP) {
    const float* Eb = Ep + ((size_t)(rb * 256 + mc0) * 64 + lane) * 4;
    f32x4 evC = *(const f32x4*)(Eb);
    bf16x8 kA[4], kB[4];
#pragma unroll
    for (int ks = 0; ks < 4; ++ks)
      kA[ks] = *(const bf16x8*)(Kw + ks * 512);      // K(0)
    for (int t = 0; t < nch; t += 2) {
      ASTEP(t, kA, kB, t + 1);
      const int tn2 = (t + 2 < nch) ? (t + 2) : (nch - 1);
      ASTEP(t + 1, kB, kA, tn2);
    }
  } else {
    // -------- fallback: R3's direct mask/weight loop --------
    const int* mbase_p = msk + (size_t)(n0 + c) * 4096 + g * 4 + (size_t)mc0 * 16;
    const float* wbase_p = wgt + (size_t)(n0 + c) * 4096 + g * 4 + (size_t)mc0 * 16;
    int4 mkN = *(const int4*)(mbase_p);
    f32x4 wvN = *(const f32x4*)(wbase_p);
    for (int t = 0; t < nch; ++t) {
      bf16x8 kf[4];
#pragma unroll
      for (int ks = 0; ks < 4; ++ks)
        kf[ks] = *(const bf16x8*)(Kw + t * 2048 + ks * 512);
      bf16x4 vf[8];
#pragma unroll
      for (int db = 0; db < 8; ++db)
        vf[db] = *(const bf16x4*)(Vw + t * 2048 + db * 256);
      const int4 mkC = mkN;
      const f32x4 wvC = wvN;
      const int tn = (t + 1 < nch) ? (t + 1) : t;
      mkN = *(const int4*)(mbase_p + tn * 16);
      wvN = *(const f32x4*)(wbase_p + tn * 16);
      f32x4 Sv = (f32x4)0.f;
#pragma unroll
      for (int ks = 0; ks < 4; ++ks) Sv = MFMA32(kf[ks], qf[ks], Sv);
      const float e0 = mkC.x ? __expf(wvC.x) : 0.f;
      const float e1 = mkC.y ? __expf(wvC.y) : 0.f;
      const float e2 = mkC.z ? __expf(wvC.z) : 0.f;
      const float e3 = mkC.w ? __expf(wvC.w) : 0.f;
      const float p0 = __expf(Sv[0]) * e0, p1 = __expf(Sv[1]) * e1;
      const float p2 = __expf(Sv[2]) * e2, p3 = __expf(Sv[3]) * e3;
      lh += (p0 + p1) + (p2 + p3);
      lb += (e0 + e1) + (e2 + e3);
      ci += (p0 * e0 + p1 * e1) + (p2 * e2 + p3 * e3);
      bf16x4 pa;
      pa[0] = f2b(p0); pa[1] = f2b(p1); pa[2] = f2b(p2); pa[3] = f2b(p3);
#pragma unroll
      for (int db = 0; db < 8; ++db)
        O[db] = MFMA16(pa, vf[db], O[db]);
    }
  }

  // reduce over g-groups (lanes ^16, ^32 share actor n=c)
  lh += __shfl_xor(lh, 16, 64); lh += __shfl_xor(lh, 32, 64);
  lb += __shfl_xor(lb, 16, 64); lb += __shfl_xor(lb, 32, 64);
  ci += __shfl_xor(ci, 16, 64); ci += __shfl_xor(ci, 32, 64);

  float inv[4];
#pragma unroll
  for (int r = 0; r < 4; ++r)
    inv[r] = 1.f / fmaxf(__shfl(lh, 4 * g + r, 64), 1e-30f);
#pragma unroll
  for (int db = 0; db < 8; ++db)
#pragma unroll
    for (int r = 0; r < 4; ++r)
      Opart[(size_t)sp * (4096 * 512) + (size_t)(n0 + g * 4 + r) * 512 +
            h * 128 + db * 16 + c] = f2b(O[db][r] * inv[r]);

  if (g == 0) {
    const int row = n0 + c;
    lpart[((size_t)sp * 4 + h) * 4096 + row] = lh;
    cipart[((size_t)sp * 4 + h) * 4096 + row] = ci;
    if (h == 0) lbpart[(size_t)sp * 4096 + row] = lb;
  }
}

// ---------------- K2b: combine splits ----------------
__global__ __launch_bounds__(256) void k_comb(
    const short* __restrict__ Opart, const float* __restrict__ lpart,
    const float* __restrict__ cipart, const float* __restrict__ lbpart,
    const int S, short* __restrict__ ctxb, float* __restrict__ validw,
    float* __restrict__ infl)
{
  const int tid = threadIdx.x;
  const int rloc = tid >> 5, cseg = tid & 31;
  const int row = blockIdx.x * 8 + rloc;
  const int col0 = cseg * 16;
  const int h = col0 >> 7;

  float l[4], ciS[4], lb = 0.f;
#pragma unroll
  for (int hh = 0; hh < 4; ++hh) { l[hh] = 0.f; ciS[hh] = 0.f; }
  for (int s = 0; s < S; ++s) {
#pragma unroll
    for (int hh = 0; hh < 4; ++hh) {
      l[hh]   += lpart[((size_t)s * 4 + hh) * 4096 + row];
      ciS[hh] += cipart[((size_t)s * 4 + hh) * 4096 + row];
    }
    lb += lbpart[(size_t)s * 4096 + row];
  }

  float acc[16];
#pragma unroll
  for (int j = 0; j < 16; ++j) acc[j] = 0.f;
  const float linv = 1.f / fmaxf(l[h], 1e-30f);
  for (int s = 0; s < S; ++s) {
    const float w_s = lpart[((size_t)s * 4 + h) * 4096 + row] * linv;
    const bf16x8 o0 = *(const bf16x8*)(Opart + (size_t)s * (4096 * 512) + (size_t)row * 512 + col0);
    const bf16x8 o1 = *(const bf16x8*)(Opart + (size_t)s * (4096 * 512) + (size_t)row * 512 + col0 + 8);
#pragma unroll
    for (int j = 0; j < 8; ++j) {
      union { unsigned u; float f; } v0, v1;
      v0.u = ((unsigned)(unsigned short)o0[j]) << 16;
      v1.u = ((unsigned)(unsigned short)o1[j]) << 16;
      acc[j]     += w_s * v0.f;
      acc[8 + j] += w_s * v1.f;
    }
  }
  bf16x8 c0, c1;
#pragma unroll
  for (int j = 0; j < 8; ++j) { c0[j] = f2b(acc[j]); c1[j] = f2b(acc[8 + j]); }
  *(bf16x8*)(ctxb + (size_t)row * 512 + col0) = c0;
  *(bf16x8*)(ctxb + (size_t)row * 512 + col0 + 8) = c1;

  if (cseg == 0) {
    validw[row] = (lb > 0.f) ? 1.f : 0.f;
    float s_ = 0.f;
#pragma unroll
    for (int hh = 0; hh < 4; ++hh) s_ += ciS[hh] / fmaxf(l[hh], 1e-30f);
    infl[row] = (lb > 0.f) ? s_ / (4.f * lb) : 0.f;
  }
}

// ---------------- K4: topic = ctx @ Wfold^T + bfold (256 wgs, direct frags) ----------------
__global__ __launch_bounds__(256) void k_out(
    const short* __restrict__ ctxb, const short* __restrict__ Wf,
    const float* __restrict__ bfo, const float* __restrict__ validw,
    float* __restrict__ topic)
{
  const int tid = threadIdx.x;
  const int lane = tid & 63, wvi = tid >> 6;
  const int m0 = blockIdx.x * 16;
  const int c = lane & 15, g = lane >> 4;

  f32x4 acc[2];
  acc[0] = (f32x4)0.f; acc[1] = (f32x4)0.f;

  for (int k0 = 0; k0 < 512; k0 += 32) {
    const bf16x8 af = *(const bf16x8*)(ctxb + (size_t)(m0 + c) * 512 + k0 + g * 8);
#pragma unroll
    for (int dbl = 0; dbl < 2; ++dbl) {
      const bf16x8 bfr = *(const bf16x8*)(Wf + (size_t)(wvi * 32 + dbl * 16 + c) * 512 + k0 + g * 8);
      acc[dbl] = MFMA32(af, bfr, acc[dbl]);
    }
  }

#pragma unroll
  for (int r = 0; r < 4; ++r) {
    const int row = m0 + g * 4 + r;
    const float va = validw[row];
#pragma unroll
    for (int dbl = 0; dbl < 2; ++dbl) {
      const int col = wvi * 32 + dbl * 16 + c;
      const float vl = (va > 0.5f) ? (acc[dbl][r] + bfo[col]) : 0.f;
      topic[(size_t)row * 128 + col] = vl;
    }
  }
}

extern "C" void kernel_launch(void* const* d_in, const int* in_sizes, int n_in,
                              void* d_out, int out_size, void* d_ws, size_t ws_size,
                              hipStream_t stream) {
  const float* a_z  = (const float*)d_in[0];
  const float* bv_z = (const float*)d_in[1];
  const int*   mask = (const int*)d_in[2];
  const float* wgt  = (const float*)d_in[3];
  const float* ipw  = (const float*)d_in[4];
  const float* ipb  = (const float*)d_in[5];
  const float* ow   = (const float*)d_in[6];
  const float* ob   = (const float*)d_in[7];
  float* topic = (float*)d_out;              // [4096 x 128]
  float* infl  = (float*)d_out + 4096 * 128; // [4096]

  const size_t MB = (size_t)1 << 20;
  char* ws = (char*)d_ws;
  short* Qb     = (short*)(ws);                    // 4 MB
  short* Kp     = (short*)(ws + 4 * MB);           // 4 MB packed K frags
  short* Vp     = (short*)(ws + 8 * MB);           // 4 MB packed V frags
  short* ctxb   = (short*)(ws + 12 * MB);          // 4 MB
  float* validw = (float*)(ws + 16 * MB);          // 16 KB
  short* Wf     = (short*)(ws + 16 * MB + (64 << 10));   // 128 KB
  float* bfo    = (float*)(ws + 16 * MB + (224 << 10));  // 512 B
  const size_t fixed = 16 * MB + (256 << 10);
  const size_t epBytes = (size_t)4096 * 4096 * 4;        // 64 MiB f32 E-table

  // per split: Opart 4MB + lpart 64KB + cipart 64KB + lbpart 16KB
  auto need = [&](int S, int ep) {
    return fixed + (ep ? epBytes : 0) + (size_t)S * (4 * MB + (144 << 10));
  };
  int S = 8, useEp = 1;
  while (S > 1 && need(S, 1) > ws_size) S >>= 1;
  if (need(S, 1) > ws_size) {            // Ep doesn't fit even at S=1: old path
    useEp = 0; S = 8;
    while (S > 1 && need(S, 0) > ws_size) S >>= 1;
  }
  float* Ep = useEp ? (float*)(ws + fixed) : nullptr;
  char* pbase = ws + fixed + (useEp ? epBytes : 0);
  short* Opart  = (short*)(pbase);
  float* lpart  = (float*)(pbase + (size_t)S * 4 * MB);
  float* cipart = (float*)(pbase + (size_t)S * 4 * MB + ((size_t)S << 16));
  float* lbpart = (float*)(pbase + (size_t)S * 4 * MB + ((size_t)S << 17));

  k_front<<<3072, 256, 0, stream>>>(a_z, bv_z, ipw, ipb, Qb, Kp, Vp,
                                    mask, wgt, Ep, ow, ob, Wf, bfo, useEp);
  if (useEp) {
    k_attn<1><<<256 * S, 256, 0, stream>>>(Qb, Kp, Vp, wgt, mask, S,
                                           Opart, lpart, cipart, lbpart, Ep);
  } else {
    k_attn<0><<<256 * S, 256, 0, stream>>>(Qb, Kp, Vp, wgt, mask, S,
                                           Opart, lpart, cipart, lbpart, Ep);
  }
  k_comb<<<512, 256, 0, stream>>>(Opart, lpart, cipart, lbpart, S, ctxb, validw, infl);
  k_out <<<256, 256, 0, stream>>>(ctxb, Wf, bfo, validw, topic);
}

// Round 17
// 316.720 us; speedup vs baseline: 1.3133x; 1.0179x over previous
//
#include <hip/hip_runtime.h>
#include <hip/hip_bf16.h>
#include <cstdint>
#include <cstddef>

// ActorHead fused pipeline, bf16 MFMA throughout.
//   K0 k_front: MERGED front-end (one launch, blocks branch):
//     [0,384)    qkv: LDS-tiled GEMM-BT [4096x1536x512], 128x128 tiles
//                (R16: was 128x64/768blk; A re-read 192MB->96MB, 2x MFMA
//                density per staging byte)
//     [384,2432) pre: E = mask ? exp(w) : 0 (f32) in MFMA-lane order
//                Ep[rb][chunk][lane][4] — R15: coalescing the m/w gather
//                (64 lines/instr -> 16) cut k_attn 196->123us.
//     [2432,2688) fold: out_w head-fold
//   K2 k_attn: split-K(S=8) flash attention, R15 structure (E-table +
//     in-iteration K/V: R16 proved K-prefetch NULL — K and V issue together,
//     one L2 round-trip/iter either way). sp = bx % S XCD-aligned splits
//     (K/V 1MB L2-resident). k_attn now ~55% of L2 BW at 4 blk/CU reg-cap.
//   K2b k_comb: merge splits; K4 k_out.
// d_out = topic[4096*128] fp32 ++ influence[4096] fp32

typedef __attribute__((ext_vector_type(8))) short bf16x8;
typedef __attribute__((ext_vector_type(4))) short bf16x4;
typedef __attribute__((ext_vector_type(4))) float f32x4;

#define MFMA32(a, b, c) __builtin_amdgcn_mfma_f32_16x16x32_bf16((a), (b), (c), 0, 0, 0)
#define MFMA16(a, b, c) __builtin_amdgcn_mfma_f32_16x16x16bf16_1k((a), (b), (c), 0, 0, 0)

static __device__ __forceinline__ short f2b(float x) {
  union { float f; unsigned u; } v; v.f = x;
  unsigned r = v.u + 0x7fffu + ((v.u >> 16) & 1u);  // RNE to bf16
  return (short)(r >> 16);
}

// ---------------- K0: merged front-end ----------------
__global__ __launch_bounds__(256) void k_front(
    const float* __restrict__ a, const float* __restrict__ kv,
    const float* __restrict__ w, const float* __restrict__ bias,
    short* __restrict__ Qb, short* __restrict__ Kp, short* __restrict__ Vp,
    const int* __restrict__ msk, const float* __restrict__ wgt,
    float* __restrict__ Ep,
    const float* __restrict__ ow, const float* __restrict__ ob,
    short* __restrict__ Wf, float* __restrict__ bfo, const int useEp)
{
  __shared__ short As[128 * 40];
  __shared__ short Bs[128 * 40];
  const int blk = blockIdx.x;
  const int tid = threadIdx.x;

  if (blk < 384) {
    // -------- qkv GEMM: 128x128 tile --------
    const int bm = blk % 32, bn = blk / 32;   // bn 0..11
    const int m0 = bm * 128, n0 = bn * 128;
    const float* __restrict__ Ain = (bn < 4) ? a : kv;
    const int lane = tid & 63, wvi = tid >> 6;
    const int wm = (wvi >> 1) * 64, wn = (wvi & 1) * 64;
    const int c = lane & 15, g = lane >> 4;
    const int sr = tid >> 1, sc = (tid & 1) * 16;  // 2 thr/row, 16 f32 each

    f32x4 acc[4][4];
#pragma unroll
    for (int i = 0; i < 4; ++i)
#pragma unroll
      for (int j = 0; j < 4; ++j) acc[i][j] = (f32x4)0.f;

    for (int k0 = 0; k0 < 512; k0 += 32) {
      const float* ap = Ain + (size_t)(m0 + sr) * 512 + k0 + sc;
      const float* bp = w + (size_t)(n0 + sr) * 512 + k0 + sc;
#pragma unroll
      for (int j = 0; j < 4; ++j) {
        f32x4 av = *(const f32x4*)(ap + 4 * j);
        bf16x4 as;
        as.x = f2b(av.x); as.y = f2b(av.y); as.z = f2b(av.z); as.w = f2b(av.w);
        *(bf16x4*)(&As[sr * 40 + sc + 4 * j]) = as;
        f32x4 bv = *(const f32x4*)(bp + 4 * j);
        bf16x4 bs;
        bs.x = f2b(bv.x); bs.y = f2b(bv.y); bs.z = f2b(bv.z); bs.w = f2b(bv.w);
        *(bf16x4*)(&Bs[sr * 40 + sc + 4 * j]) = bs;
      }
      __syncthreads();
      bf16x8 af[4], bfg[4];
#pragma unroll
      for (int t = 0; t < 4; ++t)
        af[t] = *(const bf16x8*)(&As[(wm + t * 16 + c) * 40 + g * 8]);
#pragma unroll
      for (int t = 0; t < 4; ++t)
        bfg[t] = *(const bf16x8*)(&Bs[(wn + t * 16 + c) * 40 + g * 8]);
#pragma unroll
      for (int rt = 0; rt < 4; ++rt)
#pragma unroll
        for (int ct = 0; ct < 4; ++ct)
          acc[rt][ct] = MFMA32(af[rt], bfg[ct], acc[rt][ct]);
      __syncthreads();
    }

#pragma unroll
    for (int ct = 0; ct < 4; ++ct) {
      const int col = n0 + wn + ct * 16 + c;
      const float bj = bias[col];
#pragma unroll
      for (int rt = 0; rt < 4; ++rt) {
        const int row = m0 + wm + rt * 16 + g * 4;
        const int mc = row >> 4;
        if (col < 512) {
#pragma unroll
          for (int r = 0; r < 4; ++r)
            Qb[(size_t)(row + r) * 512 + col] = f2b((acc[rt][ct][r] + bj) * 0.08838834764831843f);
        } else if (col < 1024) {
          const int colK = col - 512;
          const int h = colK >> 7, dk = colK & 127;
          const int ks = dk >> 5, gk = (dk >> 3) & 3, j = dk & 7;
          short* base = Kp + (size_t)((((h * 256 + mc) * 4 + ks) * 64) + gk * 16 + g * 4) * 8 + j;
#pragma unroll
          for (int r = 0; r < 4; ++r) base[r * 8] = f2b(acc[rt][ct][r] + bj);
        } else {
          const int colV = col - 1024;
          const int h = colV >> 7, db = (colV & 127) >> 4, cv = colV & 15;
          bf16x4 pk;
#pragma unroll
          for (int r = 0; r < 4; ++r) pk[r] = f2b(acc[rt][ct][r] + bj);
          *(bf16x4*)(Vp + (size_t)((((h * 256 + mc) * 8 + db) * 64) + g * 16 + cv) * 4) = pk;
        }
      }
    }
  } else if (blk < 2432) {
    // -------- pre: E-table (coalesced stream) --------
    if (!useEp) return;
    const int b = blk - 384;
    const int rb = b >> 3, ks8 = b & 7;
    const int c = tid >> 4;
    const int row = rb * 16 + c;
    const int lt = tid & 15;
    const int g = tid & 3;
#pragma unroll
    for (int p = 0; p < 8; ++p) {
      const int k0 = ks8 * 512 + p * 64 + lt * 4;
      const int4 mk = *(const int4*)(msk + (size_t)row * 4096 + k0);
      const f32x4 wv = *(const f32x4*)(wgt + (size_t)row * 4096 + k0);
      f32x4 ev;
      ev[0] = mk.x ? __expf(wv.x) : 0.f;
      ev[1] = mk.y ? __expf(wv.y) : 0.f;
      ev[2] = mk.z ? __expf(wv.z) : 0.f;
      ev[3] = mk.w ? __expf(wv.w) : 0.f;
      const int mc = k0 >> 4;
      *(f32x4*)(Ep + ((size_t)(rb * 256 + mc) * 64 + g * 16 + c) * 4) = ev;
    }
  } else {
    // -------- fold out_w over heads --------
    const int idx = (blk - 2432) * 256 + tid;
    if (idx < 128 * 512) {
      const int dk = idx >> 9, d = idx & 511;
      const float s = 0.25f * (ow[(size_t)dk * 512 + d] + ow[(size_t)(dk + 128) * 512 + d] +
                               ow[(size_t)(dk + 256) * 512 + d] + ow[(size_t)(dk + 384) * 512 + d]);
      Wf[(size_t)dk * 512 + d] = f2b(s);
    }
    if (idx < 128) bfo[idx] = 0.25f * (ob[idx] + ob[idx + 128] + ob[idx + 256] + ob[idx + 384]);
  }
}

// ---------------- K2: split-K flash attention (R15 loop) ----------------
template<int EP>
__global__ __launch_bounds__(256, 4) void k_attn(
    const short* __restrict__ Qb, const short* __restrict__ Kp,
    const short* __restrict__ Vp, const float* __restrict__ wgt,
    const int* __restrict__ msk, const int S,
    short* __restrict__ Opart, float* __restrict__ lpart,
    float* __restrict__ cipart, float* __restrict__ lbpart,
    const float* __restrict__ Ep)
{
  const int bx = blockIdx.x;
  // sp = bx % S: round-robin block->XCD dispatch -> one split per XCD (K/V 1MB L2).
  const int sp = bx % S, rb = bx / S;
  const int n0 = rb * 16;
  const int mlen = 4096 / S;
  const int mc0 = (sp * mlen) >> 4;
  const int nch = mlen >> 4;
  const int tid = threadIdx.x;
  const int lane = tid & 63, h = tid >> 6;
  const int c = lane & 15, g = lane >> 4;

  bf16x8 qf[4];
#pragma unroll
  for (int ks = 0; ks < 4; ++ks)
    qf[ks] = *(const bf16x8*)(Qb + (size_t)(n0 + c) * 512 + h * 128 + ks * 32 + g * 8);

  f32x4 O[8];
#pragma unroll
  for (int db = 0; db < 8; ++db) O[db] = (f32x4)0.f;
  float lh = 0.f, lb = 0.f, ci = 0.f;

  const short* Kw = Kp + (size_t)h * 524288 + (size_t)lane * 8 + (size_t)mc0 * 2048;
  const short* Vw = Vp + (size_t)h * 524288 + (size_t)lane * 4 + (size_t)mc0 * 2048;

  if (EP) {
    // E-table path: one coalesced 16B/lane load per chunk (R15: 196->123us)
    const float* Eb = Ep + ((size_t)(rb * 256 + mc0) * 64 + lane) * 4;
    f32x4 evC = *(const f32x4*)(Eb);
    for (int t = 0; t < nch; ++t) {
      bf16x8 kf[4];
#pragma unroll
      for (int ks = 0; ks < 4; ++ks)
        kf[ks] = *(const bf16x8*)(Kw + t * 2048 + ks * 512);
      bf16x4 vf[8];
#pragma unroll
      for (int db = 0; db < 8; ++db)
        vf[db] = *(const bf16x4*)(Vw + t * 2048 + db * 256);
      const f32x4 ev = evC;
      const int tn = (t + 1 < nch) ? (t + 1) : t;
      evC = *(const f32x4*)(Eb + (size_t)tn * 256);

      f32x4 Sa = (f32x4)0.f, Sb = (f32x4)0.f;
      Sa = MFMA32(kf[0], qf[0], Sa);
      Sb = MFMA32(kf[2], qf[2], Sb);
      Sa = MFMA32(kf[1], qf[1], Sa);
      Sb = MFMA32(kf[3], qf[3], Sb);
      const float p0 = __expf(Sa[0] + Sb[0]) * ev[0];
      const float p1 = __expf(Sa[1] + Sb[1]) * ev[1];
      const float p2 = __expf(Sa[2] + Sb[2]) * ev[2];
      const float p3 = __expf(Sa[3] + Sb[3]) * ev[3];
      lh += (p0 + p1) + (p2 + p3);
      lb += (ev[0] + ev[1]) + (ev[2] + ev[3]);
      ci += (p0 * ev[0] + p1 * ev[1]) + (p2 * ev[2] + p3 * ev[3]);
      bf16x4 pa;
      pa[0] = f2b(p0); pa[1] = f2b(p1); pa[2] = f2b(p2); pa[3] = f2b(p3);
#pragma unroll
      for (int db = 0; db < 8; ++db)
        O[db] = MFMA16(pa, vf[db], O[db]);
    }
  } else {
    // fallback: direct mask/weight loop
    const int* mbase_p = msk + (size_t)(n0 + c) * 4096 + g * 4 + (size_t)mc0 * 16;
    const float* wbase_p = wgt + (size_t)(n0 + c) * 4096 + g * 4 + (size_t)mc0 * 16;
    int4 mkN = *(const int4*)(mbase_p);
    f32x4 wvN = *(const f32x4*)(wbase_p);
    for (int t = 0; t < nch; ++t) {
      bf16x8 kf[4];
#pragma unroll
      for (int ks = 0; ks < 4; ++ks)
        kf[ks] = *(const bf16x8*)(Kw + t * 2048 + ks * 512);
      bf16x4 vf[8];
#pragma unroll
      for (int db = 0; db < 8; ++db)
        vf[db] = *(const bf16x4*)(Vw + t * 2048 + db * 256);
      const int4 mkC = mkN;
      const f32x4 wvC = wvN;
      const int tn = (t + 1 < nch) ? (t + 1) : t;
      mkN = *(const int4*)(mbase_p + tn * 16);
      wvN = *(const f32x4*)(wbase_p + tn * 16);
      f32x4 Sv = (f32x4)0.f;
#pragma unroll
      for (int ks = 0; ks < 4; ++ks) Sv = MFMA32(kf[ks], qf[ks], Sv);
      const float e0 = mkC.x ? __expf(wvC.x) : 0.f;
      const float e1 = mkC.y ? __expf(wvC.y) : 0.f;
      const float e2 = mkC.z ? __expf(wvC.z) : 0.f;
      const float e3 = mkC.w ? __expf(wvC.w) : 0.f;
      const float p0 = __expf(Sv[0]) * e0, p1 = __expf(Sv[1]) * e1;
      const float p2 = __expf(Sv[2]) * e2, p3 = __expf(Sv[3]) * e3;
      lh += (p0 + p1) + (p2 + p3);
      lb += (e0 + e1) + (e2 + e3);
      ci += (p0 * e0 + p1 * e1) + (p2 * e2 + p3 * e3);
      bf16x4 pa;
      pa[0] = f2b(p0); pa[1] = f2b(p1); pa[2] = f2b(p2); pa[3] = f2b(p3);
#pragma unroll
      for (int db = 0; db < 8; ++db)
        O[db] = MFMA16(pa, vf[db], O[db]);
    }
  }

  // reduce over g-groups (lanes ^16, ^32 share actor n=c)
  lh += __shfl_xor(lh, 16, 64); lh += __shfl_xor(lh, 32, 64);
  lb += __shfl_xor(lb, 16, 64); lb += __shfl_xor(lb, 32, 64);
  ci += __shfl_xor(ci, 16, 64); ci += __shfl_xor(ci, 32, 64);

  float inv[4];
#pragma unroll
  for (int r = 0; r < 4; ++r)
    inv[r] = 1.f / fmaxf(__shfl(lh, 4 * g + r, 64), 1e-30f);
#pragma unroll
  for (int db = 0; db < 8; ++db)
#pragma unroll
    for (int r = 0; r < 4; ++r)
      Opart[(size_t)sp * (4096 * 512) + (size_t)(n0 + g * 4 + r) * 512 +
            h * 128 + db * 16 + c] = f2b(O[db][r] * inv[r]);

  if (g == 0) {
    const int row = n0 + c;
    lpart[((size_t)sp * 4 + h) * 4096 + row] = lh;
    cipart[((size_t)sp * 4 + h) * 4096 + row] = ci;
    if (h == 0) lbpart[(size_t)sp * 4096 + row] = lb;
  }
}

// ---------------- K2b: combine splits ----------------
__global__ __launch_bounds__(256) void k_comb(
    const short* __restrict__ Opart, const float* __restrict__ lpart,
    const float* __restrict__ cipart, const float* __restrict__ lbpart,
    const int S, short* __restrict__ ctxb, float* __restrict__ validw,
    float* __restrict__ infl)
{
  const int tid = threadIdx.x;
  const int rloc = tid >> 5, cseg = tid & 31;
  const int row = blockIdx.x * 8 + rloc;
  const int col0 = cseg * 16;
  const int h = col0 >> 7;

  float l[4], ciS[4], lb = 0.f;
#pragma unroll
  for (int hh = 0; hh < 4; ++hh) { l[hh] = 0.f; ciS[hh] = 0.f; }
  for (int s = 0; s < S; ++s) {
#pragma unroll
    for (int hh = 0; hh < 4; ++hh) {
      l[hh]   += lpart[((size_t)s * 4 + hh) * 4096 + row];
      ciS[hh] += cipart[((size_t)s * 4 + hh) * 4096 + row];
    }
    lb += lbpart[(size_t)s * 4096 + row];
  }

  float acc[16];
#pragma unroll
  for (int j = 0; j < 16; ++j) acc[j] = 0.f;
  const float linv = 1.f / fmaxf(l[h], 1e-30f);
  for (int s = 0; s < S; ++s) {
    const float w_s = lpart[((size_t)s * 4 + h) * 4096 + row] * linv;
    const bf16x8 o0 = *(const bf16x8*)(Opart + (size_t)s * (4096 * 512) + (size_t)row * 512 + col0);
    const bf16x8 o1 = *(const bf16x8*)(Opart + (size_t)s * (4096 * 512) + (size_t)row * 512 + col0 + 8);
#pragma unroll
    for (int j = 0; j < 8; ++j) {
      union { unsigned u; float f; } v0, v1;
      v0.u = ((unsigned)(unsigned short)o0[j]) << 16;
      v1.u = ((unsigned)(unsigned short)o1[j]) << 16;
      acc[j]     += w_s * v0.f;
      acc[8 + j] += w_s * v1.f;
    }
  }
  bf16x8 c0, c1;
#pragma unroll
  for (int j = 0; j < 8; ++j) { c0[j] = f2b(acc[j]); c1[j] = f2b(acc[8 + j]); }
  *(bf16x8*)(ctxb + (size_t)row * 512 + col0) = c0;
  *(bf16x8*)(ctxb + (size_t)row * 512 + col0 + 8) = c1;

  if (cseg == 0) {
    validw[row] = (lb > 0.f) ? 1.f : 0.f;
    float s_ = 0.f;
#pragma unroll
    for (int hh = 0; hh < 4; ++hh) s_ += ciS[hh] / fmaxf(l[hh], 1e-30f);
    infl[row] = (lb > 0.f) ? s_ / (4.f * lb) : 0.f;
  }
}

// ---------------- K4: topic = ctx @ Wfold^T + bfold (256 wgs, direct frags) ----------------
__global__ __launch_bounds__(256) void k_out(
    const short* __restrict__ ctxb, const short* __restrict__ Wf,
    const float* __restrict__ bfo, const float* __restrict__ validw,
    float* __restrict__ topic)
{
  const int tid = threadIdx.x;
  const int lane = tid & 63, wvi = tid >> 6;
  const int m0 = blockIdx.x * 16;
  const int c = lane & 15, g = lane >> 4;

  f32x4 acc[2];
  acc[0] = (f32x4)0.f; acc[1] = (f32x4)0.f;

  for (int k0 = 0; k0 < 512; k0 += 32) {
    const bf16x8 af = *(const bf16x8*)(ctxb + (size_t)(m0 + c) * 512 + k0 + g * 8);
#pragma unroll
    for (int dbl = 0; dbl < 2; ++dbl) {
      const bf16x8 bfr = *(const bf16x8*)(Wf + (size_t)(wvi * 32 + dbl * 16 + c) * 512 + k0 + g * 8);
      acc[dbl] = MFMA32(af, bfr, acc[dbl]);
    }
  }

#pragma unroll
  for (int r = 0; r < 4; ++r) {
    const int row = m0 + g * 4 + r;
    const float va = validw[row];
#pragma unroll
    for (int dbl = 0; dbl < 2; ++dbl) {
      const int col = wvi * 32 + dbl * 16 + c;
      const float vl = (va > 0.5f) ? (acc[dbl][r] + bfo[col]) : 0.f;
      topic[(size_t)row * 128 + col] = vl;
    }
  }
}

extern "C" void kernel_launch(void* const* d_in, const int* in_sizes, int n_in,
                              void* d_out, int out_size, void* d_ws, size_t ws_size,
                              hipStream_t stream) {
  const float* a_z  = (const float*)d_in[0];
  const float* bv_z = (const float*)d_in[1];
  const int*   mask = (const int*)d_in[2];
  const float* wgt  = (const float*)d_in[3];
  const float* ipw  = (const float*)d_in[4];
  const float* ipb  = (const float*)d_in[5];
  const float* ow   = (const float*)d_in[6];
  const float* ob   = (const float*)d_in[7];
  float* topic = (float*)d_out;              // [4096 x 128]
  float* infl  = (float*)d_out + 4096 * 128; // [4096]

  const size_t MB = (size_t)1 << 20;
  char* ws = (char*)d_ws;
  short* Qb     = (short*)(ws);                    // 4 MB
  short* Kp     = (short*)(ws + 4 * MB);           // 4 MB packed K frags
  short* Vp     = (short*)(ws + 8 * MB);           // 4 MB packed V frags
  short* ctxb   = (short*)(ws + 12 * MB);          // 4 MB
  float* validw = (float*)(ws + 16 * MB);          // 16 KB
  short* Wf     = (short*)(ws + 16 * MB + (64 << 10));   // 128 KB
  float* bfo    = (float*)(ws + 16 * MB + (224 << 10));  // 512 B
  const size_t fixed = 16 * MB + (256 << 10);
  const size_t epBytes = (size_t)4096 * 4096 * 4;        // 64 MiB f32 E-table

  // per split: Opart 4MB + lpart 64KB + cipart 64KB + lbpart 16KB
  auto need = [&](int S, int ep) {
    return fixed + (ep ? epBytes : 0) + (size_t)S * (4 * MB + (144 << 10));
  };
  int S = 8, useEp = 1;
  while (S > 1 && need(S, 1) > ws_size) S >>= 1;
  if (need(S, 1) > ws_size) {            // Ep doesn't fit even at S=1: old path
    useEp = 0; S = 8;
    while (S > 1 && need(S, 0) > ws_size) S >>= 1;
  }
  float* Ep = useEp ? (float*)(ws + fixed) : nullptr;
  char* pbase = ws + fixed + (useEp ? epBytes : 0);
  short* Opart  = (short*)(pbase);
  float* lpart  = (float*)(pbase + (size_t)S * 4 * MB);
  float* cipart = (float*)(pbase + (size_t)S * 4 * MB + ((size_t)S << 16));
  float* lbpart = (float*)(pbase + (size_t)S * 4 * MB + ((size_t)S << 17));

  k_front<<<2688, 256, 0, stream>>>(a_z, bv_z, ipw, ipb, Qb, Kp, Vp,
                                    mask, wgt, Ep, ow, ob, Wf, bfo, useEp);
  if (useEp) {
    k_attn<1><<<256 * S, 256, 0, stream>>>(Qb, Kp, Vp, wgt, mask, S,
                                           Opart, lpart, cipart, lbpart, Ep);
  } else {
    k_attn<0><<<256 * S, 256, 0, stream>>>(Qb, Kp, Vp, wgt, mask, S,
                                           Opart, lpart, cipart, lbpart, Ep);
  }
  k_comb<<<512, 256, 0, stream>>>(Opart, lpart, cipart, lbpart, S, ctxb, validw, infl);
  k_out <<<256, 256, 0, stream>>>(ctxb, Wf, bfo, validw, topic);
}